// Round 4
// baseline (984.391 us; speedup 1.0000x reference)
//
#include <hip/hip_runtime.h>
#include <math.h>

// 2-layer GCN anomaly scorer.
// Key algebraic transform: A_norm @ (X W1) == (A_norm @ X) @ W1, so we
// aggregate 4-dim raw features over edges (4 atomics/edge) instead of the
// 32-dim transformed features (32 atomics/edge). Layer 2 feature is scalar.

__global__ void init_deg(float* __restrict__ deg, int n) {
    int i = blockIdx.x * blockDim.x + threadIdx.x;
    if (i < n) deg[i] = 1.0f;  // self-loop contributes 1 to every node's degree
}

__global__ void deg_kernel(const int* __restrict__ dst, float* __restrict__ deg, int e) {
    int i = blockIdx.x * blockDim.x + threadIdx.x;
    if (i < e) atomicAdd(&deg[dst[i]], 1.0f);
}

__global__ void dinv_init(const float* __restrict__ deg, const float* __restrict__ x,
                          float* __restrict__ dinv, float* __restrict__ agg, int n) {
    int i = blockIdx.x * blockDim.x + threadIdx.x;
    if (i < n) {
        float d = rsqrtf(deg[i]);   // deg >= 1 always (self-loop), no zero guard needed
        dinv[i] = d;
        float s = d * d;            // self-loop norm = dinv[v]*dinv[v]
        float4 xv = ((const float4*)x)[i];
        float4 a;
        a.x = s * xv.x; a.y = s * xv.y; a.z = s * xv.z; a.w = s * xv.w;
        ((float4*)agg)[i] = a;
    }
}

__global__ void scatter1(const int* __restrict__ src, const int* __restrict__ dst,
                         const float* __restrict__ x, const float* __restrict__ dinv,
                         float* __restrict__ agg, int e) {
    int i = blockIdx.x * blockDim.x + threadIdx.x;
    if (i >= e) return;
    int s = src[i], d = dst[i];
    float nrm = dinv[s] * dinv[d];
    float4 xv = ((const float4*)x)[s];
    atomicAdd(&agg[d * 4 + 0], nrm * xv.x);
    atomicAdd(&agg[d * 4 + 1], nrm * xv.y);
    atomicAdd(&agg[d * 4 + 2], nrm * xv.z);
    atomicAdd(&agg[d * 4 + 3], nrm * xv.w);
}

__global__ void transform(const float* __restrict__ agg, const float* __restrict__ W1,
                          const float* __restrict__ b1, const float* __restrict__ W2,
                          const float* __restrict__ dinv,
                          float* __restrict__ h2, float* __restrict__ out2acc, int n) {
    // W1 is [4][32] row-major, b1 [32], W2 [32][1]
    __shared__ float sW1[128];
    __shared__ float sb1[32];
    __shared__ float sW2[32];
    int t = threadIdx.x;
    if (t < 128) sW1[t] = W1[t];
    if (t < 32) { sb1[t] = b1[t]; sW2[t] = W2[t]; }
    __syncthreads();
    int i = blockIdx.x * blockDim.x + t;
    if (i >= n) return;
    float4 a = ((const float4*)agg)[i];
    float acc = 0.f;
#pragma unroll
    for (int j = 0; j < 32; ++j) {
        float o = a.x * sW1[j] + a.y * sW1[32 + j] + a.z * sW1[64 + j] + a.w * sW1[96 + j] + sb1[j];
        o = fmaxf(o, 0.f);          // ReLU
        acc += o * sW2[j];          // out1 @ W2  (scalar)
    }
    h2[i] = acc;
    float d = dinv[i];
    out2acc[i] = d * d * acc;       // seed with self-loop contribution
}

__global__ void scatter2(const int* __restrict__ src, const int* __restrict__ dst,
                         const float* __restrict__ h2, const float* __restrict__ dinv,
                         float* __restrict__ out2acc, int e) {
    int i = blockIdx.x * blockDim.x + threadIdx.x;
    if (i >= e) return;
    int s = src[i], d = dst[i];
    atomicAdd(&out2acc[d], dinv[s] * dinv[d] * h2[s]);
}

__global__ void finalize(float* __restrict__ out2acc, const float* __restrict__ b2, int n) {
    int i = blockIdx.x * blockDim.x + threadIdx.x;
    if (i < n) {
        float v = out2acc[i] + b2[0];
        out2acc[i] = 1.0f / (1.0f + expf(-v));   // sigmoid, in place on d_out
    }
}

extern "C" void kernel_launch(void* const* d_in, const int* in_sizes, int n_in,
                              void* d_out, int out_size, void* d_ws, size_t ws_size,
                              hipStream_t stream) {
    const float* x  = (const float*)d_in[0];
    const int*   ei = (const int*)d_in[1];    // harness delivers integer inputs as int32
    const float* W1 = (const float*)d_in[2];
    const float* b1 = (const float*)d_in[3];
    const float* W2 = (const float*)d_in[4];
    const float* b2 = (const float*)d_in[5];
    float* out = (float*)d_out;

    const int n = in_sizes[0] / 4;   // 100000 nodes, 4 features
    const int e = in_sizes[1] / 2;   // 3200000 edges
    const int* src = ei;             // edge_index row 0
    const int* dst = ei + e;         // edge_index row 1

    // Workspace layout (floats): deg[n] | dinv[n] | agg[4n] | h2[n]  = 7n floats
    float* deg  = (float*)d_ws;
    float* dinv = deg + n;
    float* agg  = dinv + n;
    float* h2   = agg + 4 * (size_t)n;
    float* out2acc = out;            // layer-2 accumulator lives in d_out

    const int B = 256;
    const int gn = (n + B - 1) / B;
    const int ge = (e + B - 1) / B;

    init_deg<<<gn, B, 0, stream>>>(deg, n);
    deg_kernel<<<ge, B, 0, stream>>>(dst, deg, e);
    dinv_init<<<gn, B, 0, stream>>>(deg, x, dinv, agg, n);
    scatter1<<<ge, B, 0, stream>>>(src, dst, x, dinv, agg, e);
    transform<<<gn, B, 0, stream>>>(agg, W1, b1, W2, dinv, h2, out2acc, n);
    scatter2<<<ge, B, 0, stream>>>(src, dst, h2, dinv, out2acc, e);
    finalize<<<gn, B, 0, stream>>>(out2acc, b2, n);
}

// Round 5
// 358.011 us; speedup vs baseline: 2.7496x; 2.7496x over previous
//
#include <hip/hip_runtime.h>
#include <math.h>
#include <stdint.h>

// 2-layer GCN anomaly scorer, atomic-free formulation.
//
// Round-4 evidence: device-scope fp32 atomicAdd writes through to HBM at
// ~32 B/atomic (scatter1: 12.8M atomics -> 400 MB WRITE_SIZE, 640 us,
// VALUBusy 0.24%). Any device-atomic scatter is capped at ~970 us.
// This version counting-sorts edges into 1024-node destination bins and
// accumulates in LDS (no HBM write-through), using the factorizations:
//   agg[d]  = dinv[d]*( sum_{s->d} dinv[s]*x[s] + dinv[d]*x[d] )
//   pre2[d] = dinv[d]*( sum_{s->d} g[s] + g[d] ),  g = dinv .* (relu(agg@W1+b1)@W2)

#define EB 512           // edge-chunk blocks for count/fill
#define MAXNB 128        // max bins supported
#define BINBITS 10
#define BINSZ 1024

__global__ void countK(const int* __restrict__ dst, uint32_t* __restrict__ blockCounts,
                       int e, int nb, int epb) {
    __shared__ uint32_t cnt[MAXNB];
    int t = threadIdx.x, b = blockIdx.x;
    for (int i = t; i < nb; i += blockDim.x) cnt[i] = 0;
    __syncthreads();
    int lo = b * epb, hi = min(e, lo + epb);
    for (int i = lo + t; i < hi; i += blockDim.x)
        atomicAdd(&cnt[((unsigned)dst[i]) >> BINBITS], 1u);
    __syncthreads();
    for (int i = t; i < nb; i += blockDim.x)
        blockCounts[(size_t)i * EB + b] = cnt[i];
}

__global__ void scanK(uint32_t* __restrict__ blockCounts, uint32_t* __restrict__ binStart,
                      int nb, int e) {
    // exclusive scan over M = nb*EB counts in (bin, block) order; in-place.
    const int T = 1024;
    __shared__ uint32_t tsum[T];
    int t = threadIdx.x;
    int M = nb * EB;
    int C = (M + T - 1) / T;
    int lo = t * C, hi = min(M, lo + C);
    uint32_t s = 0;
    for (int i = lo; i < hi; ++i) s += blockCounts[i];
    tsum[t] = s;
    __syncthreads();
    // Hillis-Steele inclusive scan of tsum
    for (int off = 1; off < T; off <<= 1) {
        uint32_t v = (t >= off) ? tsum[t - off] : 0u;
        __syncthreads();
        tsum[t] += v;
        __syncthreads();
    }
    uint32_t run = (t == 0) ? 0u : tsum[t - 1];   // exclusive prefix of my chunk
    for (int i = lo; i < hi; ++i) {
        uint32_t v = blockCounts[i];
        blockCounts[i] = run;
        run += v;
    }
    __syncthreads();
    for (int bin = t; bin < nb; bin += T)
        binStart[bin] = blockCounts[(size_t)bin * EB];
    if (t == 0) binStart[nb] = (uint32_t)e;
}

__global__ void fillK(const int* __restrict__ src, const int* __restrict__ dst,
                      const uint32_t* __restrict__ blockCounts,
                      uint32_t* __restrict__ records, int e, int nb, int epb) {
    __shared__ uint32_t cur[MAXNB];
    int t = threadIdx.x, b = blockIdx.x;
    for (int i = t; i < nb; i += blockDim.x)
        cur[i] = blockCounts[(size_t)i * EB + b];
    __syncthreads();
    int lo = b * epb, hi = min(e, lo + epb);
    for (int i = lo + t; i < hi; i += blockDim.x) {
        unsigned d = (unsigned)dst[i];
        unsigned s = (unsigned)src[i];
        unsigned bin = d >> BINBITS;
        uint32_t slot = atomicAdd(&cur[bin], 1u);       // LDS atomic
        records[slot] = (s << BINBITS) | (d & (BINSZ - 1));
    }
}

__global__ __launch_bounds__(1024)
void degK(const uint32_t* __restrict__ records, const uint32_t* __restrict__ binStart,
          float* __restrict__ dinv, int n) {
    __shared__ uint32_t hist[BINSZ];
    int t = threadIdx.x, bin = blockIdx.x;
    for (int i = t; i < BINSZ; i += blockDim.x) hist[i] = 0u;
    __syncthreads();
    uint32_t lo = binStart[bin], hi = binStart[bin + 1];
    for (uint32_t i = lo + t; i < hi; i += blockDim.x)
        atomicAdd(&hist[records[i] & (BINSZ - 1)], 1u);
    __syncthreads();
    int base = bin << BINBITS;
    for (int i = t; i < BINSZ; i += blockDim.x) {
        int g = base + i;
        if (g < n) dinv[g] = rsqrtf(1.0f + (float)hist[i]);  // +1 = self-loop
    }
}

__global__ __launch_bounds__(1024)
void aggK(const uint32_t* __restrict__ records, const uint32_t* __restrict__ binStart,
          const float4* __restrict__ x4, const float* __restrict__ dinv,
          const float* __restrict__ W1, const float* __restrict__ b1,
          const float* __restrict__ W2, float* __restrict__ g, int n) {
    __shared__ float acc[4 * BINSZ];   // feature-major: acc[j*BINSZ + dl] (bank-spread)
    __shared__ float sW1[128], sb1[32], sW2[32];
    int t = threadIdx.x, bin = blockIdx.x;
    for (int i = t; i < 4 * BINSZ; i += blockDim.x) acc[i] = 0.f;
    if (t < 128) sW1[t] = W1[t];
    else if (t < 160) sb1[t - 128] = b1[t - 128];
    else if (t < 192) sW2[t - 160] = W2[t - 160];
    __syncthreads();
    uint32_t lo = binStart[bin], hi = binStart[bin + 1];
    for (uint32_t i = lo + t; i < hi; i += blockDim.x) {
        uint32_t r = records[i];
        unsigned s = r >> BINBITS, dl = r & (BINSZ - 1);
        float ds = dinv[s];
        float4 xv = x4[s];
        atomicAdd(&acc[0 * BINSZ + dl], ds * xv.x);
        atomicAdd(&acc[1 * BINSZ + dl], ds * xv.y);
        atomicAdd(&acc[2 * BINSZ + dl], ds * xv.z);
        atomicAdd(&acc[3 * BINSZ + dl], ds * xv.w);
    }
    __syncthreads();
    int base = bin << BINBITS;
    for (int i = t; i < BINSZ; i += blockDim.x) {
        int gg = base + i;
        if (gg >= n) continue;
        float dd = dinv[gg];
        float4 xv = x4[gg];
        float a0 = dd * (acc[0 * BINSZ + i] + dd * xv.x);
        float a1 = dd * (acc[1 * BINSZ + i] + dd * xv.y);
        float a2 = dd * (acc[2 * BINSZ + i] + dd * xv.z);
        float a3 = dd * (acc[3 * BINSZ + i] + dd * xv.w);
        float hv = 0.f;
#pragma unroll
        for (int j = 0; j < 32; ++j) {
            float o = a0 * sW1[j] + a1 * sW1[32 + j] + a2 * sW1[64 + j] + a3 * sW1[96 + j] + sb1[j];
            o = fmaxf(o, 0.f);
            hv += o * sW2[j];
        }
        g[gg] = dd * hv;
    }
}

__global__ __launch_bounds__(1024)
void outK(const uint32_t* __restrict__ records, const uint32_t* __restrict__ binStart,
          const float* __restrict__ g, const float* __restrict__ dinv,
          const float* __restrict__ b2, float* __restrict__ out, int n) {
    __shared__ float accg[BINSZ];
    int t = threadIdx.x, bin = blockIdx.x;
    for (int i = t; i < BINSZ; i += blockDim.x) accg[i] = 0.f;
    __syncthreads();
    uint32_t lo = binStart[bin], hi = binStart[bin + 1];
    for (uint32_t i = lo + t; i < hi; i += blockDim.x) {
        uint32_t r = records[i];
        atomicAdd(&accg[r & (BINSZ - 1)], g[r >> BINBITS]);
    }
    __syncthreads();
    int base = bin << BINBITS;
    float bb = b2[0];
    for (int i = t; i < BINSZ; i += blockDim.x) {
        int gg = base + i;
        if (gg < n) {
            float dd = dinv[gg];
            float v = dd * (accg[i] + g[gg]) + bb;
            out[gg] = 1.0f / (1.0f + expf(-v));
        }
    }
}

extern "C" void kernel_launch(void* const* d_in, const int* in_sizes, int n_in,
                              void* d_out, int out_size, void* d_ws, size_t ws_size,
                              hipStream_t stream) {
    const float* x  = (const float*)d_in[0];
    const int*   ei = (const int*)d_in[1];    // int32 (verified: round-4 passed with this cast)
    const float* W1 = (const float*)d_in[2];
    const float* b1 = (const float*)d_in[3];
    const float* W2 = (const float*)d_in[4];
    const float* b2 = (const float*)d_in[5];
    float* out = (float*)d_out;

    const int n = in_sizes[0] / 4;            // 100000
    const int e = in_sizes[1] / 2;            // 3200000
    const int* src = ei;
    const int* dst = ei + e;

    const int nb  = (n + BINSZ - 1) >> BINBITS;   // 98 bins
    const int epb = (e + EB - 1) / EB;

    // Workspace: records[e] | blockCounts[nb*EB] | binStart[nb+1] | dinv[n] | g[n]
    uint32_t* records     = (uint32_t*)d_ws;
    uint32_t* blockCounts = records + e;
    uint32_t* binStart    = blockCounts + (size_t)nb * EB;
    float*    dinv        = (float*)(binStart + nb + 1);
    float*    gbuf        = dinv + n;

    countK<<<EB, 256, 0, stream>>>(dst, blockCounts, e, nb, epb);
    scanK <<<1, 1024, 0, stream>>>(blockCounts, binStart, nb, e);
    fillK <<<EB, 256, 0, stream>>>(src, dst, blockCounts, records, e, nb, epb);
    degK  <<<nb, 1024, 0, stream>>>(records, binStart, dinv, n);
    aggK  <<<nb, 1024, 0, stream>>>(records, binStart, (const float4*)x, dinv,
                                    W1, b1, W2, gbuf, n);
    outK  <<<nb, 1024, 0, stream>>>(records, binStart, gbuf, dinv, b2, out, n);
}

// Round 6
// 315.198 us; speedup vs baseline: 3.1231x; 1.1358x over previous
//
#include <hip/hip_runtime.h>
#include <math.h>
#include <stdint.h>

// 2-layer GCN anomaly scorer — binned counting-sort + LDS accumulation.
// R4: device atomics write through HBM (32B/atomic) -> 984us cap. R5: binned
// LDS version 358us, but aggK (98 blocks, 2 gathers/edge) was latency-bound
// at 17% occupancy. R6: finer bins (256 nodes), SPLIT-way edge-chunk blocks
// with partial-buffer merges (grid ~1564), and a precomputed y4[s]=dinv[s]*x[s]
// table so the hot sweep does ONE float4 gather per edge.
//
// Math: agg[d] = dinv[d]*(sum_{s->d} y4[s] + y4[d]),  y4 = dinv.*x
//       g      = dinv .* (relu(agg@W1+b1)@W2)
//       out[d] = sigmoid(dinv[d]*(sum_{s->d} g[s] + g[d]) + b2)

#define BINBITS 8
#define BINSZ   256
#define NBMAX   512
#define EBC     256      // blocks for count/fill edge chunking
#define THR     256

// ---------------- sort phase ----------------

__global__ void countK(const int* __restrict__ dst, uint32_t* __restrict__ bc,
                       int e, int nb) {
    __shared__ uint32_t cnt[NBMAX];
    int t = threadIdx.x, b = blockIdx.x;
    for (int i = t; i < nb; i += THR) cnt[i] = 0;
    __syncthreads();
    int epb = (e + EBC - 1) / EBC;
    int lo = b * epb, hi = min(e, lo + epb);
    for (int i = lo + t; i < hi; i += THR)
        atomicAdd(&cnt[((unsigned)dst[i]) >> BINBITS], 1u);
    __syncthreads();
    for (int i = t; i < nb; i += THR) bc[(size_t)i * EBC + b] = cnt[i];
}

__global__ void scanK(uint32_t* __restrict__ bc, uint32_t* __restrict__ binStart,
                      int nb, int e) {
    const int T = 1024;
    __shared__ uint32_t tsum[T];
    int t = threadIdx.x;
    int M = nb * EBC;
    int C = (M + T - 1) / T;
    int lo = t * C, hi = min(M, lo + C);
    uint32_t s = 0;
    for (int i = lo; i < hi; ++i) s += bc[i];
    tsum[t] = s;
    __syncthreads();
    for (int off = 1; off < T; off <<= 1) {
        uint32_t v = (t >= off) ? tsum[t - off] : 0u;
        __syncthreads();
        tsum[t] += v;
        __syncthreads();
    }
    uint32_t run = (t == 0) ? 0u : tsum[t - 1];
    for (int i = lo; i < hi; ++i) {
        uint32_t v = bc[i];
        bc[i] = run;
        run += v;
    }
    __syncthreads();
    for (int bin = t; bin < nb; bin += T) binStart[bin] = bc[(size_t)bin * EBC];
    if (t == 0) binStart[nb] = (uint32_t)e;
}

__global__ void fillK(const int* __restrict__ src, const int* __restrict__ dst,
                      const uint32_t* __restrict__ bc,
                      uint32_t* __restrict__ records, int e, int nb) {
    __shared__ uint32_t cur[NBMAX];
    int t = threadIdx.x, b = blockIdx.x;
    for (int i = t; i < nb; i += THR) cur[i] = bc[(size_t)i * EBC + b];
    __syncthreads();
    int epb = (e + EBC - 1) / EBC;
    int lo = b * epb, hi = min(e, lo + epb);
    for (int i = lo + t; i < hi; i += THR) {
        unsigned d = (unsigned)dst[i];
        unsigned s = (unsigned)src[i];
        uint32_t slot = atomicAdd(&cur[d >> BINBITS], 1u);   // LDS atomic
        records[slot] = (s << BINBITS) | (d & (BINSZ - 1));
    }
}

// ---------------- degree / dinv / y4 ----------------

__global__ void deg_part(const uint32_t* __restrict__ records,
                         const uint32_t* __restrict__ binStart,
                         uint32_t* __restrict__ histP, int split) {
    __shared__ uint32_t hist[BINSZ];
    int t = threadIdx.x;
    int bin = blockIdx.x / split, sub = blockIdx.x % split;
    hist[t] = 0u;
    __syncthreads();
    uint32_t lo = binStart[bin], hi = binStart[bin + 1];
    uint32_t chunk = (hi - lo + split - 1) / split;
    uint32_t slo = lo + sub * chunk;
    uint32_t shi = min(hi, slo + chunk);
    for (uint32_t i = slo + t; i < shi; i += THR)
        atomicAdd(&hist[records[i] & (BINSZ - 1)], 1u);
    __syncthreads();
    histP[(size_t)blockIdx.x * BINSZ + t] = hist[t];
}

__global__ void mergeDinvY(const uint32_t* __restrict__ histP,
                           const float4* __restrict__ x4,
                           float* __restrict__ dinv, float4* __restrict__ y4,
                           int split, int n) {
    int t = threadIdx.x, bin = blockIdx.x;
    int node = (bin << BINBITS) + t;
    if (node >= n) return;
    uint32_t c = 0;
    for (int s = 0; s < split; ++s)
        c += histP[(size_t)(bin * split + s) * BINSZ + t];
    float dd = rsqrtf(1.0f + (float)c);
    dinv[node] = dd;
    float4 xv = x4[node];
    y4[node] = make_float4(dd * xv.x, dd * xv.y, dd * xv.z, dd * xv.w);
}

template <int USEY>
__global__ void deg_inline(const uint32_t* __restrict__ records,
                           const uint32_t* __restrict__ binStart,
                           const float4* __restrict__ x4,
                           float* __restrict__ dinv, float4* __restrict__ y4, int n) {
    __shared__ uint32_t hist[BINSZ];
    int t = threadIdx.x, bin = blockIdx.x;
    hist[t] = 0u;
    __syncthreads();
    uint32_t lo = binStart[bin], hi = binStart[bin + 1];
    for (uint32_t i = lo + t; i < hi; i += THR)
        atomicAdd(&hist[records[i] & (BINSZ - 1)], 1u);
    __syncthreads();
    int node = (bin << BINBITS) + t;
    if (node >= n) return;
    float dd = rsqrtf(1.0f + (float)hist[t]);
    dinv[node] = dd;
    if (USEY) {
        float4 xv = x4[node];
        y4[node] = make_float4(dd * xv.x, dd * xv.y, dd * xv.z, dd * xv.w);
    }
}

// ---------------- layer-1 aggregation + transform ----------------

__global__ void agg_part(const uint32_t* __restrict__ records,
                         const uint32_t* __restrict__ binStart,
                         const float4* __restrict__ y4,
                         float* __restrict__ aggP, int split) {
    __shared__ float acc[4 * BINSZ];
    int t = threadIdx.x;
    int bin = blockIdx.x / split, sub = blockIdx.x % split;
    for (int i = t; i < 4 * BINSZ; i += THR) acc[i] = 0.f;
    __syncthreads();
    uint32_t lo = binStart[bin], hi = binStart[bin + 1];
    uint32_t chunk = (hi - lo + split - 1) / split;
    uint32_t slo = lo + sub * chunk;
    uint32_t shi = min(hi, slo + chunk);
    for (uint32_t i = slo + t; i < shi; i += THR) {
        uint32_t r = records[i];
        unsigned s = r >> BINBITS, dl = r & (BINSZ - 1);
        float4 yv = y4[s];
        atomicAdd(&acc[0 * BINSZ + dl], yv.x);
        atomicAdd(&acc[1 * BINSZ + dl], yv.y);
        atomicAdd(&acc[2 * BINSZ + dl], yv.z);
        atomicAdd(&acc[3 * BINSZ + dl], yv.w);
    }
    __syncthreads();
    float* p = aggP + (size_t)blockIdx.x * (4 * BINSZ);
    for (int i = t; i < 4 * BINSZ; i += THR) p[i] = acc[i];
}

__global__ void mergeAggT(const float* __restrict__ aggP,
                          const float* __restrict__ dinv, const float4* __restrict__ y4,
                          const float* __restrict__ W1, const float* __restrict__ b1,
                          const float* __restrict__ W2,
                          float* __restrict__ g, int split, int n) {
    __shared__ float sW1[128], sb1[32], sW2[32];
    int t = threadIdx.x, bin = blockIdx.x;
    if (t < 128) sW1[t] = W1[t];
    else if (t < 160) sb1[t - 128] = b1[t - 128];
    else if (t < 192) sW2[t - 160] = W2[t - 160];
    __syncthreads();
    int node = (bin << BINBITS) + t;
    if (node >= n) return;
    float T0 = 0, T1 = 0, T2 = 0, T3 = 0;
    for (int s = 0; s < split; ++s) {
        const float* p = aggP + (size_t)(bin * split + s) * (4 * BINSZ);
        T0 += p[0 * BINSZ + t];
        T1 += p[1 * BINSZ + t];
        T2 += p[2 * BINSZ + t];
        T3 += p[3 * BINSZ + t];
    }
    float dd = dinv[node];
    float4 yv = y4[node];
    float a0 = dd * (T0 + yv.x), a1 = dd * (T1 + yv.y);
    float a2 = dd * (T2 + yv.z), a3 = dd * (T3 + yv.w);
    float hv = 0.f;
#pragma unroll
    for (int j = 0; j < 32; ++j) {
        float o = fmaf(a0, sW1[j], fmaf(a1, sW1[32 + j],
                  fmaf(a2, sW1[64 + j], fmaf(a3, sW1[96 + j], sb1[j]))));
        hv += fmaxf(o, 0.f) * sW2[j];
    }
    g[node] = dd * hv;
}

template <int USEY>
__global__ void agg_inline(const uint32_t* __restrict__ records,
                           const uint32_t* __restrict__ binStart,
                           const float4* __restrict__ y4, const float* __restrict__ dinv,
                           const float4* __restrict__ x4,
                           const float* __restrict__ W1, const float* __restrict__ b1,
                           const float* __restrict__ W2,
                           float* __restrict__ g, int n) {
    __shared__ float acc[4 * BINSZ];
    __shared__ float sW1[128], sb1[32], sW2[32];
    int t = threadIdx.x, bin = blockIdx.x;
    for (int i = t; i < 4 * BINSZ; i += THR) acc[i] = 0.f;
    if (t < 128) sW1[t] = W1[t];
    else if (t < 160) sb1[t - 128] = b1[t - 128];
    else if (t < 192) sW2[t - 160] = W2[t - 160];
    __syncthreads();
    uint32_t lo = binStart[bin], hi = binStart[bin + 1];
    for (uint32_t i = lo + t; i < hi; i += THR) {
        uint32_t r = records[i];
        unsigned s = r >> BINBITS, dl = r & (BINSZ - 1);
        if (USEY) {
            float4 yv = y4[s];
            atomicAdd(&acc[0 * BINSZ + dl], yv.x);
            atomicAdd(&acc[1 * BINSZ + dl], yv.y);
            atomicAdd(&acc[2 * BINSZ + dl], yv.z);
            atomicAdd(&acc[3 * BINSZ + dl], yv.w);
        } else {
            float ds = dinv[s];
            float4 xv = x4[s];
            atomicAdd(&acc[0 * BINSZ + dl], ds * xv.x);
            atomicAdd(&acc[1 * BINSZ + dl], ds * xv.y);
            atomicAdd(&acc[2 * BINSZ + dl], ds * xv.z);
            atomicAdd(&acc[3 * BINSZ + dl], ds * xv.w);
        }
    }
    __syncthreads();
    int node = (bin << BINBITS) + t;
    if (node >= n) return;
    float dd = dinv[node];
    float b0, b1v, b2v, b3;
    if (USEY) {
        float4 yv = y4[node];
        b0 = yv.x; b1v = yv.y; b2v = yv.z; b3 = yv.w;
    } else {
        float4 xv = x4[node];
        b0 = dd * xv.x; b1v = dd * xv.y; b2v = dd * xv.z; b3 = dd * xv.w;
    }
    float a0 = dd * (acc[0 * BINSZ + t] + b0), a1 = dd * (acc[1 * BINSZ + t] + b1v);
    float a2 = dd * (acc[2 * BINSZ + t] + b2v), a3 = dd * (acc[3 * BINSZ + t] + b3);
    float hv = 0.f;
#pragma unroll
    for (int j = 0; j < 32; ++j) {
        float o = fmaf(a0, sW1[j], fmaf(a1, sW1[32 + j],
                  fmaf(a2, sW1[64 + j], fmaf(a3, sW1[96 + j], sb1[j]))));
        hv += fmaxf(o, 0.f) * sW2[j];
    }
    g[node] = dd * hv;
}

// ---------------- layer-2 ----------------

__global__ void out_part(const uint32_t* __restrict__ records,
                         const uint32_t* __restrict__ binStart,
                         const float* __restrict__ g,
                         float* __restrict__ outP, int split) {
    __shared__ float accg[BINSZ];
    int t = threadIdx.x;
    int bin = blockIdx.x / split, sub = blockIdx.x % split;
    accg[t] = 0.f;
    __syncthreads();
    uint32_t lo = binStart[bin], hi = binStart[bin + 1];
    uint32_t chunk = (hi - lo + split - 1) / split;
    uint32_t slo = lo + sub * chunk;
    uint32_t shi = min(hi, slo + chunk);
    for (uint32_t i = slo + t; i < shi; i += THR) {
        uint32_t r = records[i];
        atomicAdd(&accg[r & (BINSZ - 1)], g[r >> BINBITS]);
    }
    __syncthreads();
    outP[(size_t)blockIdx.x * BINSZ + t] = accg[t];
}

__global__ void mergeOutK(const float* __restrict__ outP, const float* __restrict__ g,
                          const float* __restrict__ dinv, const float* __restrict__ b2,
                          float* __restrict__ out, int split, int n) {
    int t = threadIdx.x, bin = blockIdx.x;
    int node = (bin << BINBITS) + t;
    if (node >= n) return;
    float s = 0.f;
    for (int k = 0; k < split; ++k)
        s += outP[(size_t)(bin * split + k) * BINSZ + t];
    float v = dinv[node] * (s + g[node]) + b2[0];
    out[node] = 1.0f / (1.0f + expf(-v));
}

__global__ void out_inline(const uint32_t* __restrict__ records,
                           const uint32_t* __restrict__ binStart,
                           const float* __restrict__ g, const float* __restrict__ dinv,
                           const float* __restrict__ b2, float* __restrict__ out, int n) {
    __shared__ float accg[BINSZ];
    int t = threadIdx.x, bin = blockIdx.x;
    accg[t] = 0.f;
    __syncthreads();
    uint32_t lo = binStart[bin], hi = binStart[bin + 1];
    for (uint32_t i = lo + t; i < hi; i += THR) {
        uint32_t r = records[i];
        atomicAdd(&accg[r & (BINSZ - 1)], g[r >> BINBITS]);
    }
    __syncthreads();
    int node = (bin << BINBITS) + t;
    if (node >= n) return;
    float v = dinv[node] * (accg[t] + g[node]) + b2[0];
    out[node] = 1.0f / (1.0f + expf(-v));
}

// ---------------- launcher ----------------

extern "C" void kernel_launch(void* const* d_in, const int* in_sizes, int n_in,
                              void* d_out, int out_size, void* d_ws, size_t ws_size,
                              hipStream_t stream) {
    const float* x  = (const float*)d_in[0];
    const int*   ei = (const int*)d_in[1];
    const float* W1 = (const float*)d_in[2];
    const float* b1 = (const float*)d_in[3];
    const float* W2 = (const float*)d_in[4];
    const float* b2 = (const float*)d_in[5];
    float* out = (float*)d_out;

    const int n = in_sizes[0] / 4;            // 100000
    const int e = in_sizes[1] / 2;            // 3200000
    const int* src = ei;
    const int* dst = ei + e;

    const int nb = (n + BINSZ - 1) >> BINBITS;   // 391

    // fixed regions
    size_t recB  = (size_t)e * 4;
    size_t bcB   = (size_t)nb * EBC * 4;
    size_t bsB   = ((size_t)nb + 1) * 4;
    bsB = (bsB + 15) & ~(size_t)15;
    size_t dinvB = (size_t)n * 4;
    dinvB = (dinvB + 15) & ~(size_t)15;
    size_t gB    = (size_t)n * 4;
    gB = (gB + 15) & ~(size_t)15;
    size_t y4B   = (size_t)n * 16;
    size_t fixed = recB + bcB + bsB + dinvB + gB;

    auto arena_sz = [&](int split) { return (size_t)nb * split * 4 * BINSZ * 4; };

    int split; int useY;
    if (ws_size >= fixed + y4B + arena_sz(4))      { split = 4; useY = 1; }
    else if (ws_size >= fixed + y4B + arena_sz(2)) { split = 2; useY = 1; }
    else if (ws_size >= fixed + y4B)               { split = 1; useY = 1; }
    else                                           { split = 1; useY = 0; }

    char* p = (char*)d_ws;
    uint32_t* records  = (uint32_t*)p;            p += recB;
    uint32_t* bc       = (uint32_t*)p;            p += bcB;
    uint32_t* binStart = (uint32_t*)p;            p += bsB;
    float*    dinv     = (float*)p;               p += dinvB;
    float*    gbuf     = (float*)p;               p += gB;
    float4*   y4       = (float4*)p;              if (useY) p += y4B;
    float*    arena    = (float*)p;               // partials (hist/agg/out share)

    const float4* x4 = (const float4*)x;

    countK<<<EBC, THR, 0, stream>>>(dst, bc, e, nb);
    scanK <<<1, 1024, 0, stream>>>(bc, binStart, nb, e);
    fillK <<<EBC, THR, 0, stream>>>(src, dst, bc, records, e, nb);

    if (split > 1) {
        deg_part<<<nb * split, THR, 0, stream>>>(records, binStart, (uint32_t*)arena, split);
        mergeDinvY<<<nb, THR, 0, stream>>>((const uint32_t*)arena, x4, dinv, y4, split, n);
        agg_part<<<nb * split, THR, 0, stream>>>(records, binStart, y4, arena, split);
        mergeAggT<<<nb, THR, 0, stream>>>(arena, dinv, y4, W1, b1, W2, gbuf, split, n);
        out_part<<<nb * split, THR, 0, stream>>>(records, binStart, gbuf, arena, split);
        mergeOutK<<<nb, THR, 0, stream>>>(arena, gbuf, dinv, b2, out, split, n);
    } else if (useY) {
        deg_inline<1><<<nb, THR, 0, stream>>>(records, binStart, x4, dinv, y4, n);
        agg_inline<1><<<nb, THR, 0, stream>>>(records, binStart, y4, dinv, x4, W1, b1, W2, gbuf, n);
        out_inline<<<nb, THR, 0, stream>>>(records, binStart, gbuf, dinv, b2, out, n);
    } else {
        deg_inline<0><<<nb, THR, 0, stream>>>(records, binStart, x4, dinv, nullptr, n);
        agg_inline<0><<<nb, THR, 0, stream>>>(records, binStart, nullptr, dinv, x4, W1, b1, W2, gbuf, n);
        out_inline<<<nb, THR, 0, stream>>>(records, binStart, gbuf, dinv, b2, out, n);
    }
}

// Round 7
// 160.205 us; speedup vs baseline: 6.1446x; 1.9675x over previous
//
#include <hip/hip_runtime.h>
#include <math.h>
#include <stdint.h>

// 2-layer GCN anomaly scorer — binned counting-sort + LDS accumulation.
// R4: device atomics write through HBM (32B/atomic) -> 984us. R5: binned LDS
// 358us (aggK latency-bound, 98 blocks). R6: 256-node bins + split-4 edge
// sweeps -> 315us, but the single-block flat scan was 164us (1 CU, serial).
// R7: two-level scan (per-bin coalesced LDS scan + tiny bin-sum scan).
//
// Math: agg[d] = dinv[d]*(sum_{s->d} y4[s] + y4[d]),  y4 = dinv.*x
//       g      = dinv .* (relu(agg@W1+b1)@W2)
//       out[d] = sigmoid(dinv[d]*(sum_{s->d} g[s] + g[d]) + b2)

#define BINBITS 8
#define BINSZ   256
#define NBMAX   512
#define EBC     256      // edge-chunk blocks for count/fill
#define THR     256

// ---------------- sort phase ----------------

__global__ void countK(const int* __restrict__ dst, uint32_t* __restrict__ bc,
                       int e, int nb) {
    __shared__ uint32_t cnt[NBMAX];
    int t = threadIdx.x, b = blockIdx.x;
    for (int i = t; i < nb; i += THR) cnt[i] = 0;
    __syncthreads();
    int epb = (e + EBC - 1) / EBC;
    int lo = b * epb, hi = min(e, lo + epb);
    for (int i = lo + t; i < hi; i += THR)
        atomicAdd(&cnt[((unsigned)dst[i]) >> BINBITS], 1u);
    __syncthreads();
    for (int i = t; i < nb; i += THR) bc[(size_t)i * EBC + b] = cnt[i];
}

// per-bin exclusive scan of the EBC per-block counts (coalesced, in place)
__global__ void scan1K(uint32_t* __restrict__ bc, uint32_t* __restrict__ binSum) {
    __shared__ uint32_t s[EBC];
    int t = threadIdx.x, bin = blockIdx.x;
    uint32_t v = bc[(size_t)bin * EBC + t];
    s[t] = v;
    __syncthreads();
    for (int off = 1; off < EBC; off <<= 1) {
        uint32_t u = (t >= off) ? s[t - off] : 0u;
        __syncthreads();
        s[t] += u;
        __syncthreads();
    }
    bc[(size_t)bin * EBC + t] = s[t] - v;           // exclusive
    if (t == EBC - 1) binSum[bin] = s[t];           // bin total
}

// exclusive scan of bin sums -> binStart
__global__ void scan2K(const uint32_t* __restrict__ binSum,
                       uint32_t* __restrict__ binStart, int nb, int e) {
    __shared__ uint32_t s[512];
    int t = threadIdx.x;
    uint32_t v = (t < nb) ? binSum[t] : 0u;
    s[t] = v;
    __syncthreads();
    for (int off = 1; off < 512; off <<= 1) {
        uint32_t u = (t >= off) ? s[t - off] : 0u;
        __syncthreads();
        s[t] += u;
        __syncthreads();
    }
    if (t < nb) binStart[t] = s[t] - v;
    if (t == 0) binStart[nb] = (uint32_t)e;
}

__global__ void fillK(const int* __restrict__ src, const int* __restrict__ dst,
                      const uint32_t* __restrict__ bc,
                      const uint32_t* __restrict__ binStart,
                      uint32_t* __restrict__ records, int e, int nb) {
    __shared__ uint32_t cur[NBMAX];
    int t = threadIdx.x, b = blockIdx.x;
    for (int i = t; i < nb; i += THR)
        cur[i] = bc[(size_t)i * EBC + b] + binStart[i];
    __syncthreads();
    int epb = (e + EBC - 1) / EBC;
    int lo = b * epb, hi = min(e, lo + epb);
    for (int i = lo + t; i < hi; i += THR) {
        unsigned d = (unsigned)dst[i];
        unsigned s = (unsigned)src[i];
        uint32_t slot = atomicAdd(&cur[d >> BINBITS], 1u);   // LDS atomic
        records[slot] = (s << BINBITS) | (d & (BINSZ - 1));
    }
}

// ---------------- degree / dinv / y4 ----------------

__global__ void deg_part(const uint32_t* __restrict__ records,
                         const uint32_t* __restrict__ binStart,
                         uint32_t* __restrict__ histP, int split) {
    __shared__ uint32_t hist[BINSZ];
    int t = threadIdx.x;
    int bin = blockIdx.x / split, sub = blockIdx.x % split;
    hist[t] = 0u;
    __syncthreads();
    uint32_t lo = binStart[bin], hi = binStart[bin + 1];
    uint32_t chunk = (hi - lo + split - 1) / split;
    uint32_t slo = lo + sub * chunk;
    uint32_t shi = min(hi, slo + chunk);
    for (uint32_t i = slo + t; i < shi; i += THR)
        atomicAdd(&hist[records[i] & (BINSZ - 1)], 1u);
    __syncthreads();
    histP[(size_t)blockIdx.x * BINSZ + t] = hist[t];
}

__global__ void mergeDinvY(const uint32_t* __restrict__ histP,
                           const float4* __restrict__ x4,
                           float* __restrict__ dinv, float4* __restrict__ y4,
                           int split, int n) {
    int t = threadIdx.x, bin = blockIdx.x;
    int node = (bin << BINBITS) + t;
    if (node >= n) return;
    uint32_t c = 0;
    for (int s = 0; s < split; ++s)
        c += histP[(size_t)(bin * split + s) * BINSZ + t];
    float dd = rsqrtf(1.0f + (float)c);
    dinv[node] = dd;
    float4 xv = x4[node];
    y4[node] = make_float4(dd * xv.x, dd * xv.y, dd * xv.z, dd * xv.w);
}

template <int USEY>
__global__ void deg_inline(const uint32_t* __restrict__ records,
                           const uint32_t* __restrict__ binStart,
                           const float4* __restrict__ x4,
                           float* __restrict__ dinv, float4* __restrict__ y4, int n) {
    __shared__ uint32_t hist[BINSZ];
    int t = threadIdx.x, bin = blockIdx.x;
    hist[t] = 0u;
    __syncthreads();
    uint32_t lo = binStart[bin], hi = binStart[bin + 1];
    for (uint32_t i = lo + t; i < hi; i += THR)
        atomicAdd(&hist[records[i] & (BINSZ - 1)], 1u);
    __syncthreads();
    int node = (bin << BINBITS) + t;
    if (node >= n) return;
    float dd = rsqrtf(1.0f + (float)hist[t]);
    dinv[node] = dd;
    if (USEY) {
        float4 xv = x4[node];
        y4[node] = make_float4(dd * xv.x, dd * xv.y, dd * xv.z, dd * xv.w);
    }
}

// ---------------- layer-1 aggregation + transform ----------------

__global__ void agg_part(const uint32_t* __restrict__ records,
                         const uint32_t* __restrict__ binStart,
                         const float4* __restrict__ y4,
                         float* __restrict__ aggP, int split) {
    __shared__ float acc[4 * BINSZ];
    int t = threadIdx.x;
    int bin = blockIdx.x / split, sub = blockIdx.x % split;
    for (int i = t; i < 4 * BINSZ; i += THR) acc[i] = 0.f;
    __syncthreads();
    uint32_t lo = binStart[bin], hi = binStart[bin + 1];
    uint32_t chunk = (hi - lo + split - 1) / split;
    uint32_t slo = lo + sub * chunk;
    uint32_t shi = min(hi, slo + chunk);
    for (uint32_t i = slo + t; i < shi; i += THR) {
        uint32_t r = records[i];
        unsigned s = r >> BINBITS, dl = r & (BINSZ - 1);
        float4 yv = y4[s];
        atomicAdd(&acc[0 * BINSZ + dl], yv.x);
        atomicAdd(&acc[1 * BINSZ + dl], yv.y);
        atomicAdd(&acc[2 * BINSZ + dl], yv.z);
        atomicAdd(&acc[3 * BINSZ + dl], yv.w);
    }
    __syncthreads();
    float* p = aggP + (size_t)blockIdx.x * (4 * BINSZ);
    for (int i = t; i < 4 * BINSZ; i += THR) p[i] = acc[i];
}

__global__ void mergeAggT(const float* __restrict__ aggP,
                          const float* __restrict__ dinv, const float4* __restrict__ y4,
                          const float* __restrict__ W1, const float* __restrict__ b1,
                          const float* __restrict__ W2,
                          float* __restrict__ g, int split, int n) {
    __shared__ float sW1[128], sb1[32], sW2[32];
    int t = threadIdx.x, bin = blockIdx.x;
    if (t < 128) sW1[t] = W1[t];
    else if (t < 160) sb1[t - 128] = b1[t - 128];
    else if (t < 192) sW2[t - 160] = W2[t - 160];
    __syncthreads();
    int node = (bin << BINBITS) + t;
    if (node >= n) return;
    float T0 = 0, T1 = 0, T2 = 0, T3 = 0;
    for (int s = 0; s < split; ++s) {
        const float* p = aggP + (size_t)(bin * split + s) * (4 * BINSZ);
        T0 += p[0 * BINSZ + t];
        T1 += p[1 * BINSZ + t];
        T2 += p[2 * BINSZ + t];
        T3 += p[3 * BINSZ + t];
    }
    float dd = dinv[node];
    float4 yv = y4[node];
    float a0 = dd * (T0 + yv.x), a1 = dd * (T1 + yv.y);
    float a2 = dd * (T2 + yv.z), a3 = dd * (T3 + yv.w);
    float hv = 0.f;
#pragma unroll
    for (int j = 0; j < 32; ++j) {
        float o = fmaf(a0, sW1[j], fmaf(a1, sW1[32 + j],
                  fmaf(a2, sW1[64 + j], fmaf(a3, sW1[96 + j], sb1[j]))));
        hv += fmaxf(o, 0.f) * sW2[j];
    }
    g[node] = dd * hv;
}

template <int USEY>
__global__ void agg_inline(const uint32_t* __restrict__ records,
                           const uint32_t* __restrict__ binStart,
                           const float4* __restrict__ y4, const float* __restrict__ dinv,
                           const float4* __restrict__ x4,
                           const float* __restrict__ W1, const float* __restrict__ b1,
                           const float* __restrict__ W2,
                           float* __restrict__ g, int n) {
    __shared__ float acc[4 * BINSZ];
    __shared__ float sW1[128], sb1[32], sW2[32];
    int t = threadIdx.x, bin = blockIdx.x;
    for (int i = t; i < 4 * BINSZ; i += THR) acc[i] = 0.f;
    if (t < 128) sW1[t] = W1[t];
    else if (t < 160) sb1[t - 128] = b1[t - 128];
    else if (t < 192) sW2[t - 160] = W2[t - 160];
    __syncthreads();
    uint32_t lo = binStart[bin], hi = binStart[bin + 1];
    for (uint32_t i = lo + t; i < hi; i += THR) {
        uint32_t r = records[i];
        unsigned s = r >> BINBITS, dl = r & (BINSZ - 1);
        if (USEY) {
            float4 yv = y4[s];
            atomicAdd(&acc[0 * BINSZ + dl], yv.x);
            atomicAdd(&acc[1 * BINSZ + dl], yv.y);
            atomicAdd(&acc[2 * BINSZ + dl], yv.z);
            atomicAdd(&acc[3 * BINSZ + dl], yv.w);
        } else {
            float ds = dinv[s];
            float4 xv = x4[s];
            atomicAdd(&acc[0 * BINSZ + dl], ds * xv.x);
            atomicAdd(&acc[1 * BINSZ + dl], ds * xv.y);
            atomicAdd(&acc[2 * BINSZ + dl], ds * xv.z);
            atomicAdd(&acc[3 * BINSZ + dl], ds * xv.w);
        }
    }
    __syncthreads();
    int node = (bin << BINBITS) + t;
    if (node >= n) return;
    float dd = dinv[node];
    float b0, b1v, b2v, b3;
    if (USEY) {
        float4 yv = y4[node];
        b0 = yv.x; b1v = yv.y; b2v = yv.z; b3 = yv.w;
    } else {
        float4 xv = x4[node];
        b0 = dd * xv.x; b1v = dd * xv.y; b2v = dd * xv.z; b3 = dd * xv.w;
    }
    float a0 = dd * (acc[0 * BINSZ + t] + b0), a1 = dd * (acc[1 * BINSZ + t] + b1v);
    float a2 = dd * (acc[2 * BINSZ + t] + b2v), a3 = dd * (acc[3 * BINSZ + t] + b3);
    float hv = 0.f;
#pragma unroll
    for (int j = 0; j < 32; ++j) {
        float o = fmaf(a0, sW1[j], fmaf(a1, sW1[32 + j],
                  fmaf(a2, sW1[64 + j], fmaf(a3, sW1[96 + j], sb1[j]))));
        hv += fmaxf(o, 0.f) * sW2[j];
    }
    g[node] = dd * hv;
}

// ---------------- layer-2 ----------------

__global__ void out_part(const uint32_t* __restrict__ records,
                         const uint32_t* __restrict__ binStart,
                         const float* __restrict__ g,
                         float* __restrict__ outP, int split) {
    __shared__ float accg[BINSZ];
    int t = threadIdx.x;
    int bin = blockIdx.x / split, sub = blockIdx.x % split;
    accg[t] = 0.f;
    __syncthreads();
    uint32_t lo = binStart[bin], hi = binStart[bin + 1];
    uint32_t chunk = (hi - lo + split - 1) / split;
    uint32_t slo = lo + sub * chunk;
    uint32_t shi = min(hi, slo + chunk);
    for (uint32_t i = slo + t; i < shi; i += THR) {
        uint32_t r = records[i];
        atomicAdd(&accg[r & (BINSZ - 1)], g[r >> BINBITS]);
    }
    __syncthreads();
    outP[(size_t)blockIdx.x * BINSZ + t] = accg[t];
}

__global__ void mergeOutK(const float* __restrict__ outP, const float* __restrict__ g,
                          const float* __restrict__ dinv, const float* __restrict__ b2,
                          float* __restrict__ out, int split, int n) {
    int t = threadIdx.x, bin = blockIdx.x;
    int node = (bin << BINBITS) + t;
    if (node >= n) return;
    float s = 0.f;
    for (int k = 0; k < split; ++k)
        s += outP[(size_t)(bin * split + k) * BINSZ + t];
    float v = dinv[node] * (s + g[node]) + b2[0];
    out[node] = 1.0f / (1.0f + expf(-v));
}

__global__ void out_inline(const uint32_t* __restrict__ records,
                           const uint32_t* __restrict__ binStart,
                           const float* __restrict__ g, const float* __restrict__ dinv,
                           const float* __restrict__ b2, float* __restrict__ out, int n) {
    __shared__ float accg[BINSZ];
    int t = threadIdx.x, bin = blockIdx.x;
    accg[t] = 0.f;
    __syncthreads();
    uint32_t lo = binStart[bin], hi = binStart[bin + 1];
    for (uint32_t i = lo + t; i < hi; i += THR) {
        uint32_t r = records[i];
        atomicAdd(&accg[r & (BINSZ - 1)], g[r >> BINBITS]);
    }
    __syncthreads();
    int node = (bin << BINBITS) + t;
    if (node >= n) return;
    float v = dinv[node] * (accg[t] + g[node]) + b2[0];
    out[node] = 1.0f / (1.0f + expf(-v));
}

// ---------------- launcher ----------------

extern "C" void kernel_launch(void* const* d_in, const int* in_sizes, int n_in,
                              void* d_out, int out_size, void* d_ws, size_t ws_size,
                              hipStream_t stream) {
    const float* x  = (const float*)d_in[0];
    const int*   ei = (const int*)d_in[1];
    const float* W1 = (const float*)d_in[2];
    const float* b1 = (const float*)d_in[3];
    const float* W2 = (const float*)d_in[4];
    const float* b2 = (const float*)d_in[5];
    float* out = (float*)d_out;

    const int n = in_sizes[0] / 4;            // 100000
    const int e = in_sizes[1] / 2;            // 3200000
    const int* src = ei;
    const int* dst = ei + e;

    const int nb = (n + BINSZ - 1) >> BINBITS;   // 391

    // fixed regions
    size_t recB  = (size_t)e * 4;
    size_t bcB   = (size_t)nb * EBC * 4;
    size_t bsB   = ((size_t)(2 * nb + 1) * 4 + 15) & ~(size_t)15;  // binStart[nb+1] + binSum[nb]
    size_t dinvB = ((size_t)n * 4 + 15) & ~(size_t)15;
    size_t gB    = ((size_t)n * 4 + 15) & ~(size_t)15;
    size_t y4B   = (size_t)n * 16;
    size_t fixed = recB + bcB + bsB + dinvB + gB;

    auto arena_sz = [&](int split) { return (size_t)nb * split * 4 * BINSZ * 4; };

    int split; int useY;
    if (ws_size >= fixed + y4B + arena_sz(4))      { split = 4; useY = 1; }
    else if (ws_size >= fixed + y4B + arena_sz(2)) { split = 2; useY = 1; }
    else if (ws_size >= fixed + y4B)               { split = 1; useY = 1; }
    else                                           { split = 1; useY = 0; }

    char* p = (char*)d_ws;
    uint32_t* records  = (uint32_t*)p;            p += recB;
    uint32_t* bc       = (uint32_t*)p;            p += bcB;
    uint32_t* binStart = (uint32_t*)p;            p += bsB;
    uint32_t* binSum   = binStart + nb + 1;
    float*    dinv     = (float*)p;               p += dinvB;
    float*    gbuf     = (float*)p;               p += gB;
    float4*   y4       = (float4*)p;              if (useY) p += y4B;
    float*    arena    = (float*)p;               // partials (hist/agg/out share)

    const float4* x4 = (const float4*)x;

    countK<<<EBC, THR, 0, stream>>>(dst, bc, e, nb);
    scan1K<<<nb, EBC, 0, stream>>>(bc, binSum);
    scan2K<<<1, 512, 0, stream>>>(binSum, binStart, nb, e);
    fillK <<<EBC, THR, 0, stream>>>(src, dst, bc, binStart, records, e, nb);

    if (split > 1) {
        deg_part<<<nb * split, THR, 0, stream>>>(records, binStart, (uint32_t*)arena, split);
        mergeDinvY<<<nb, THR, 0, stream>>>((const uint32_t*)arena, x4, dinv, y4, split, n);
        agg_part<<<nb * split, THR, 0, stream>>>(records, binStart, y4, arena, split);
        mergeAggT<<<nb, THR, 0, stream>>>(arena, dinv, y4, W1, b1, W2, gbuf, split, n);
        out_part<<<nb * split, THR, 0, stream>>>(records, binStart, gbuf, arena, split);
        mergeOutK<<<nb, THR, 0, stream>>>(arena, gbuf, dinv, b2, out, split, n);
    } else if (useY) {
        deg_inline<1><<<nb, THR, 0, stream>>>(records, binStart, x4, dinv, y4, n);
        agg_inline<1><<<nb, THR, 0, stream>>>(records, binStart, y4, dinv, x4, W1, b1, W2, gbuf, n);
        out_inline<<<nb, THR, 0, stream>>>(records, binStart, gbuf, dinv, b2, out, n);
    } else {
        deg_inline<0><<<nb, THR, 0, stream>>>(records, binStart, x4, dinv, nullptr, n);
        agg_inline<0><<<nb, THR, 0, stream>>>(records, binStart, nullptr, dinv, x4, W1, b1, W2, gbuf, n);
        out_inline<<<nb, THR, 0, stream>>>(records, binStart, gbuf, dinv, b2, out, n);
    }
}

// Round 8
// 115.263 us; speedup vs baseline: 8.5404x; 1.3899x over previous
//
#include <hip/hip_runtime.h>
#include <math.h>
#include <stdint.h>

// 2-layer GCN anomaly scorer — binned counting-sort + LDS accumulation.
// R4: device atomics write through HBM -> 984us. R5: binned LDS 358us.
// R6: 256-bins + split4 -> 315us (flat scan 164us). R7: 2-level scan -> 160us;
// agg_part 78us latency-bound (occ 40%, VGPR 8, 4 LDS atomics/edge serial).
// R8: split 8 + EBC 1024 (occupancy), unroll-2 (ILP), and u64 fixed-point
// packed atomics (4 f32 -> 2 u64 LDS atomics per edge; deterministic).
//
// Math: agg[d] = dinv[d]*(sum_{s->d} y[s] + y[d]),  y = dinv.*x
//       g      = dinv .* (relu(agg@W1+b1)@W2)
//       out[d] = sigmoid(dinv[d]*(sum_{s->d} g[s] + g[d]) + b2)
// Fixed-point: q(v) = rn((v+16)*2^21); fields (f0,f1),(f2,f3) in two u64s.
// Max biased sum: 21*2^21*deg(<=~90) < 2^32 -> no field overflow.

#define BINBITS 8
#define BINSZ   256
#define NBMAX   512
#define EBC     1024     // edge-chunk blocks for count/fill
#define THR     256
#define QS      2097152.0f   // 2^21
#define QB      16.0f

__device__ __forceinline__ uint32_t packq(float v) {
    return __float2uint_rn(fmaf(v, QS, QB * QS));
}

// ---------------- sort phase ----------------

__global__ void countK(const int* __restrict__ dst, uint32_t* __restrict__ bc,
                       int e, int nb) {
    __shared__ uint32_t cnt[NBMAX];
    int t = threadIdx.x, b = blockIdx.x;
    for (int i = t; i < nb; i += THR) cnt[i] = 0;
    __syncthreads();
    int epb = (e + EBC - 1) / EBC;
    int lo = b * epb, hi = min(e, lo + epb);
    for (int i = lo + t; i < hi; i += THR)
        atomicAdd(&cnt[((unsigned)dst[i]) >> BINBITS], 1u);
    __syncthreads();
    for (int i = t; i < nb; i += THR) bc[(size_t)i * EBC + b] = cnt[i];
}

// per-bin exclusive scan of the EBC per-block counts (block == EBC threads)
__global__ void scan1K(uint32_t* __restrict__ bc, uint32_t* __restrict__ binSum) {
    __shared__ uint32_t s[EBC];
    int t = threadIdx.x, bin = blockIdx.x;
    uint32_t v = bc[(size_t)bin * EBC + t];
    s[t] = v;
    __syncthreads();
    for (int off = 1; off < EBC; off <<= 1) {
        uint32_t u = (t >= off) ? s[t - off] : 0u;
        __syncthreads();
        s[t] += u;
        __syncthreads();
    }
    bc[(size_t)bin * EBC + t] = s[t] - v;           // exclusive
    if (t == EBC - 1) binSum[bin] = s[t];
}

__global__ void scan2K(const uint32_t* __restrict__ binSum,
                       uint32_t* __restrict__ binStart, int nb, int e) {
    __shared__ uint32_t s[512];
    int t = threadIdx.x;
    uint32_t v = (t < nb) ? binSum[t] : 0u;
    s[t] = v;
    __syncthreads();
    for (int off = 1; off < 512; off <<= 1) {
        uint32_t u = (t >= off) ? s[t - off] : 0u;
        __syncthreads();
        s[t] += u;
        __syncthreads();
    }
    if (t < nb) binStart[t] = s[t] - v;
    if (t == 0) binStart[nb] = (uint32_t)e;
}

__global__ void fillK(const int* __restrict__ src, const int* __restrict__ dst,
                      const uint32_t* __restrict__ bc,
                      const uint32_t* __restrict__ binStart,
                      uint32_t* __restrict__ records, int e, int nb) {
    __shared__ uint32_t cur[NBMAX];
    int t = threadIdx.x, b = blockIdx.x;
    for (int i = t; i < nb; i += THR)
        cur[i] = bc[(size_t)i * EBC + b] + binStart[i];
    __syncthreads();
    int epb = (e + EBC - 1) / EBC;
    int lo = b * epb, hi = min(e, lo + epb);
    for (int i = lo + t; i < hi; i += THR) {
        unsigned d = (unsigned)dst[i];
        unsigned s = (unsigned)src[i];
        uint32_t slot = atomicAdd(&cur[d >> BINBITS], 1u);   // LDS atomic
        records[slot] = (s << BINBITS) | (d & (BINSZ - 1));
    }
}

// ---------------- degree / dinv / packed y ----------------

__global__ void deg_part(const uint32_t* __restrict__ records,
                         const uint32_t* __restrict__ binStart,
                         uint32_t* __restrict__ histP, int split) {
    __shared__ uint32_t hist[BINSZ];
    int t = threadIdx.x;
    int bin = blockIdx.x / split, sub = blockIdx.x % split;
    hist[t] = 0u;
    __syncthreads();
    uint32_t lo = binStart[bin], hi = binStart[bin + 1];
    uint32_t chunk = (hi - lo + split - 1) / split;
    uint32_t slo = lo + sub * chunk;
    uint32_t shi = min(hi, slo + chunk);
    for (uint32_t i = slo + t; i < shi; i += THR)
        atomicAdd(&hist[records[i] & (BINSZ - 1)], 1u);
    __syncthreads();
    histP[(size_t)blockIdx.x * BINSZ + t] = hist[t];
}

__global__ void mergeDinvY(const uint32_t* __restrict__ histP,
                           const float4* __restrict__ x4,
                           float* __restrict__ dinv, uint32_t* __restrict__ deg,
                           ulonglong2* __restrict__ y4q, int split, int n) {
    int t = threadIdx.x, bin = blockIdx.x;
    int node = (bin << BINBITS) + t;
    if (node >= n) return;
    uint32_t c = 0;
    for (int s = 0; s < split; ++s)
        c += histP[(size_t)(bin * split + s) * BINSZ + t];
    float dd = rsqrtf(1.0f + (float)c);
    dinv[node] = dd;
    deg[node] = c;
    float4 xv = x4[node];
    uint32_t q0 = packq(dd * xv.x), q1 = packq(dd * xv.y);
    uint32_t q2 = packq(dd * xv.z), q3 = packq(dd * xv.w);
    ulonglong2 p;
    p.x = ((unsigned long long)q1 << 32) | q0;
    p.y = ((unsigned long long)q3 << 32) | q2;
    y4q[node] = p;
}

// ---------------- layer-1 aggregation (packed u64 atomics) ----------------

__global__ void agg_part(const uint32_t* __restrict__ records,
                         const uint32_t* __restrict__ binStart,
                         const ulonglong2* __restrict__ y4q,
                         unsigned long long* __restrict__ aggP, int split) {
    __shared__ unsigned long long acc[2 * BINSZ];
    int t = threadIdx.x;
    int bin = blockIdx.x / split, sub = blockIdx.x % split;
    acc[t] = 0ull;
    acc[BINSZ + t] = 0ull;
    __syncthreads();
    uint32_t lo = binStart[bin], hi = binStart[bin + 1];
    uint32_t chunk = (hi - lo + split - 1) / split;
    uint32_t slo = lo + sub * chunk;
    uint32_t shi = min(hi, slo + chunk);
    uint32_t i = slo + t;
    for (; i + THR < shi; i += 2 * THR) {          // unroll-2 for ILP
        uint32_t r0 = records[i];
        uint32_t r1 = records[i + THR];
        ulonglong2 y0 = y4q[r0 >> BINBITS];
        ulonglong2 y1 = y4q[r1 >> BINBITS];
        unsigned d0 = r0 & (BINSZ - 1), d1 = r1 & (BINSZ - 1);
        atomicAdd(&acc[d0], y0.x);
        atomicAdd(&acc[BINSZ + d0], y0.y);
        atomicAdd(&acc[d1], y1.x);
        atomicAdd(&acc[BINSZ + d1], y1.y);
    }
    if (i < shi) {
        uint32_t r0 = records[i];
        ulonglong2 y0 = y4q[r0 >> BINBITS];
        unsigned d0 = r0 & (BINSZ - 1);
        atomicAdd(&acc[d0], y0.x);
        atomicAdd(&acc[BINSZ + d0], y0.y);
    }
    __syncthreads();
    unsigned long long* p = aggP + (size_t)blockIdx.x * (2 * BINSZ);
    p[t] = acc[t];
    p[BINSZ + t] = acc[BINSZ + t];
}

__global__ void mergeAggT(const unsigned long long* __restrict__ aggP,
                          const float* __restrict__ dinv, const uint32_t* __restrict__ deg,
                          const float4* __restrict__ x4,
                          const float* __restrict__ W1, const float* __restrict__ b1,
                          const float* __restrict__ W2,
                          float* __restrict__ g, int split, int n) {
    __shared__ float sW1[128], sb1[32], sW2[32];
    int t = threadIdx.x, bin = blockIdx.x;
    if (t < 128) sW1[t] = W1[t];
    else if (t < 160) sb1[t - 128] = b1[t - 128];
    else if (t < 192) sW2[t - 160] = W2[t - 160];
    __syncthreads();
    int node = (bin << BINBITS) + t;
    if (node >= n) return;
    unsigned long long s0lo = 0, s0hi = 0, s1lo = 0, s1hi = 0;
    for (int s = 0; s < split; ++s) {
        const unsigned long long* p = aggP + (size_t)(bin * split + s) * (2 * BINSZ);
        unsigned long long P0 = p[t], P1 = p[BINSZ + t];
        s0lo += (uint32_t)P0; s0hi += (uint32_t)(P0 >> 32);
        s1lo += (uint32_t)P1; s1hi += (uint32_t)(P1 >> 32);
    }
    float degf = (float)deg[node];
    const float inv = 1.0f / QS;
    float bias = QB * degf;
    float T0 = (float)s0lo * inv - bias;
    float T1 = (float)s0hi * inv - bias;
    float T2 = (float)s1lo * inv - bias;
    float T3 = (float)s1hi * inv - bias;
    float dd = dinv[node];
    float4 xv = x4[node];
    float a0 = dd * (T0 + dd * xv.x), a1 = dd * (T1 + dd * xv.y);
    float a2 = dd * (T2 + dd * xv.z), a3 = dd * (T3 + dd * xv.w);
    float hv = 0.f;
#pragma unroll
    for (int j = 0; j < 32; ++j) {
        float o = fmaf(a0, sW1[j], fmaf(a1, sW1[32 + j],
                  fmaf(a2, sW1[64 + j], fmaf(a3, sW1[96 + j], sb1[j]))));
        hv += fmaxf(o, 0.f) * sW2[j];
    }
    g[node] = dd * hv;
}

// ---------------- layer-2 ----------------

__global__ void out_part(const uint32_t* __restrict__ records,
                         const uint32_t* __restrict__ binStart,
                         const float* __restrict__ g,
                         float* __restrict__ outP, int split) {
    __shared__ float accg[BINSZ];
    int t = threadIdx.x;
    int bin = blockIdx.x / split, sub = blockIdx.x % split;
    accg[t] = 0.f;
    __syncthreads();
    uint32_t lo = binStart[bin], hi = binStart[bin + 1];
    uint32_t chunk = (hi - lo + split - 1) / split;
    uint32_t slo = lo + sub * chunk;
    uint32_t shi = min(hi, slo + chunk);
    uint32_t i = slo + t;
    for (; i + THR < shi; i += 2 * THR) {
        uint32_t r0 = records[i];
        uint32_t r1 = records[i + THR];
        float g0 = g[r0 >> BINBITS];
        float g1 = g[r1 >> BINBITS];
        atomicAdd(&accg[r0 & (BINSZ - 1)], g0);
        atomicAdd(&accg[r1 & (BINSZ - 1)], g1);
    }
    if (i < shi) {
        uint32_t r0 = records[i];
        atomicAdd(&accg[r0 & (BINSZ - 1)], g[r0 >> BINBITS]);
    }
    __syncthreads();
    outP[(size_t)blockIdx.x * BINSZ + t] = accg[t];
}

__global__ void mergeOutK(const float* __restrict__ outP, const float* __restrict__ g,
                          const float* __restrict__ dinv, const float* __restrict__ b2,
                          float* __restrict__ out, int split, int n) {
    int t = threadIdx.x, bin = blockIdx.x;
    int node = (bin << BINBITS) + t;
    if (node >= n) return;
    float s = 0.f;
    for (int k = 0; k < split; ++k)
        s += outP[(size_t)(bin * split + k) * BINSZ + t];
    float v = dinv[node] * (s + g[node]) + b2[0];
    out[node] = 1.0f / (1.0f + expf(-v));
}

// ---------------- launcher ----------------

extern "C" void kernel_launch(void* const* d_in, const int* in_sizes, int n_in,
                              void* d_out, int out_size, void* d_ws, size_t ws_size,
                              hipStream_t stream) {
    const float* x  = (const float*)d_in[0];
    const int*   ei = (const int*)d_in[1];
    const float* W1 = (const float*)d_in[2];
    const float* b1 = (const float*)d_in[3];
    const float* W2 = (const float*)d_in[4];
    const float* b2 = (const float*)d_in[5];
    float* out = (float*)d_out;

    const int n = in_sizes[0] / 4;            // 100000
    const int e = in_sizes[1] / 2;            // 3200000
    const int* src = ei;
    const int* dst = ei + e;

    const int nb = (n + BINSZ - 1) >> BINBITS;   // 391

    size_t recB  = ((size_t)e * 4 + 15) & ~(size_t)15;
    size_t bcB   = ((size_t)nb * EBC * 4 + 15) & ~(size_t)15;
    size_t bsB   = ((size_t)(2 * nb + 2) * 4 + 15) & ~(size_t)15;
    size_t dinvB = ((size_t)n * 4 + 15) & ~(size_t)15;
    size_t degB  = ((size_t)n * 4 + 15) & ~(size_t)15;
    size_t gB    = ((size_t)n * 4 + 15) & ~(size_t)15;
    size_t y4qB  = ((size_t)n * 16 + 15) & ~(size_t)15;
    size_t fixed = recB + bcB + bsB + dinvB + degB + gB + y4qB;

    auto arena_sz = [&](int s) { return (size_t)nb * s * (2 * BINSZ) * 8; };

    int split;
    if      (ws_size >= fixed + arena_sz(8)) split = 8;
    else if (ws_size >= fixed + arena_sz(4)) split = 4;
    else if (ws_size >= fixed + arena_sz(2)) split = 2;
    else                                     split = 1;

    char* p = (char*)d_ws;
    uint32_t*   records  = (uint32_t*)p;      p += recB;
    uint32_t*   bc       = (uint32_t*)p;      p += bcB;
    uint32_t*   binStart = (uint32_t*)p;      p += bsB;
    uint32_t*   binSum   = binStart + nb + 1;
    float*      dinv     = (float*)p;         p += dinvB;
    uint32_t*   deg      = (uint32_t*)p;      p += degB;
    float*      gbuf     = (float*)p;         p += gB;
    ulonglong2* y4q      = (ulonglong2*)p;    p += y4qB;
    void*       arena    = (void*)p;          // partials (deg/agg/out reuse sequentially)

    const float4* x4 = (const float4*)x;

    countK<<<EBC, THR, 0, stream>>>(dst, bc, e, nb);
    scan1K<<<nb, EBC, 0, stream>>>(bc, binSum);
    scan2K<<<1, 512, 0, stream>>>(binSum, binStart, nb, e);
    fillK <<<EBC, THR, 0, stream>>>(src, dst, bc, binStart, records, e, nb);

    deg_part<<<nb * split, THR, 0, stream>>>(records, binStart, (uint32_t*)arena, split);
    mergeDinvY<<<nb, THR, 0, stream>>>((const uint32_t*)arena, x4, dinv, deg, y4q, split, n);
    agg_part<<<nb * split, THR, 0, stream>>>(records, binStart, y4q,
                                             (unsigned long long*)arena, split);
    mergeAggT<<<nb, THR, 0, stream>>>((const unsigned long long*)arena, dinv, deg, x4,
                                      W1, b1, W2, gbuf, split, n);
    out_part<<<nb * split, THR, 0, stream>>>(records, binStart, gbuf, (float*)arena, split);
    mergeOutK<<<nb, THR, 0, stream>>>((const float*)arena, gbuf, dinv, b2, out, split, n);
}

// Round 9
// 105.070 us; speedup vs baseline: 9.3689x; 1.0970x over previous
//
#include <hip/hip_runtime.h>
#include <math.h>
#include <stdint.h>

// 2-layer GCN anomaly scorer — binned counting-sort + LDS accumulation.
// R4: device atomics write through HBM -> 984us. R5: binned LDS 358us.
// R6: 256-bins + split4 -> 315us. R7: 2-level scan -> 160us. R8: split8 +
// u64 packed LDS atomics -> 115us, but EBC=1024 made fillK's record scatter
// 6x write-amplified (75MB for 12.8MB of records; cross-XCD line ping-pong).
// R9: EBC back to 256, XCD-contiguous chunk swizzle in fillK, exact int64
// conversion in mergeAggT, deg_part unroll-2.
//
// Math: agg[d] = dinv[d]*(sum_{s->d} y[s] + y[d]),  y = dinv.*x
//       g      = dinv .* (relu(agg@W1+b1)@W2)
//       out[d] = sigmoid(dinv[d]*(sum_{s->d} g[s] + g[d]) + b2)
// Fixed-point: q(v) = rn((v+16)*2^21); fields (f0,f1),(f2,f3) in two u64s.
// Max biased field sum: 21*2^21*deg(<=~90) ~ 3.1e9 < 2^32 -> no overflow.

#define BINBITS 8
#define BINSZ   256
#define NBMAX   512
#define EBC     256      // edge-chunk blocks for count/fill
#define THR     256
#define QS      2097152.0f   // 2^21
#define QB      16.0f

__device__ __forceinline__ uint32_t packq(float v) {
    return __float2uint_rn(fmaf(v, QS, QB * QS));
}

// ---------------- sort phase ----------------

__global__ void countK(const int* __restrict__ dst, uint32_t* __restrict__ bc,
                       int e, int nb) {
    __shared__ uint32_t cnt[NBMAX];
    int t = threadIdx.x, b = blockIdx.x;
    for (int i = t; i < nb; i += THR) cnt[i] = 0;
    __syncthreads();
    int epb = (e + EBC - 1) / EBC;
    int lo = b * epb, hi = min(e, lo + epb);
    for (int i = lo + t; i < hi; i += THR)
        atomicAdd(&cnt[((unsigned)dst[i]) >> BINBITS], 1u);
    __syncthreads();
    for (int i = t; i < nb; i += THR) bc[(size_t)i * EBC + b] = cnt[i];
}

// per-bin exclusive scan of the EBC per-block counts (block == EBC threads)
__global__ void scan1K(uint32_t* __restrict__ bc, uint32_t* __restrict__ binSum) {
    __shared__ uint32_t s[EBC];
    int t = threadIdx.x, bin = blockIdx.x;
    uint32_t v = bc[(size_t)bin * EBC + t];
    s[t] = v;
    __syncthreads();
    for (int off = 1; off < EBC; off <<= 1) {
        uint32_t u = (t >= off) ? s[t - off] : 0u;
        __syncthreads();
        s[t] += u;
        __syncthreads();
    }
    bc[(size_t)bin * EBC + t] = s[t] - v;           // exclusive
    if (t == EBC - 1) binSum[bin] = s[t];
}

__global__ void scan2K(const uint32_t* __restrict__ binSum,
                       uint32_t* __restrict__ binStart, int nb, int e) {
    __shared__ uint32_t s[512];
    int t = threadIdx.x;
    uint32_t v = (t < nb) ? binSum[t] : 0u;
    s[t] = v;
    __syncthreads();
    for (int off = 1; off < 512; off <<= 1) {
        uint32_t u = (t >= off) ? s[t - off] : 0u;
        __syncthreads();
        s[t] += u;
        __syncthreads();
    }
    if (t < nb) binStart[t] = s[t] - v;
    if (t == 0) binStart[nb] = (uint32_t)e;
}

__global__ void fillK(const int* __restrict__ src, const int* __restrict__ dst,
                      const uint32_t* __restrict__ bc,
                      const uint32_t* __restrict__ binStart,
                      uint32_t* __restrict__ records, int e, int nb) {
    __shared__ uint32_t cur[NBMAX];
    int t = threadIdx.x;
    // XCD-contiguous chunk swizzle: blocks on the same XCD (bid%8 equal under
    // round-robin dispatch) process CONTIGUOUS edge chunks, so record cache
    // lines shared by adjacent chunks stay within one XCD's L2.
    int b = (blockIdx.x & 7) * (EBC / 8) + (blockIdx.x >> 3);
    for (int i = t; i < nb; i += THR)
        cur[i] = bc[(size_t)i * EBC + b] + binStart[i];
    __syncthreads();
    int epb = (e + EBC - 1) / EBC;
    int lo = b * epb, hi = min(e, lo + epb);
    for (int i = lo + t; i < hi; i += THR) {
        unsigned d = (unsigned)dst[i];
        unsigned s = (unsigned)src[i];
        uint32_t slot = atomicAdd(&cur[d >> BINBITS], 1u);   // LDS atomic
        records[slot] = (s << BINBITS) | (d & (BINSZ - 1));
    }
}

// ---------------- degree / dinv / packed y ----------------

__global__ void deg_part(const uint32_t* __restrict__ records,
                         const uint32_t* __restrict__ binStart,
                         uint32_t* __restrict__ histP, int split) {
    __shared__ uint32_t hist[BINSZ];
    int t = threadIdx.x;
    int bin = blockIdx.x / split, sub = blockIdx.x % split;
    hist[t] = 0u;
    __syncthreads();
    uint32_t lo = binStart[bin], hi = binStart[bin + 1];
    uint32_t chunk = (hi - lo + split - 1) / split;
    uint32_t slo = lo + sub * chunk;
    uint32_t shi = min(hi, slo + chunk);
    uint32_t i = slo + t;
    for (; i + THR < shi; i += 2 * THR) {
        uint32_t r0 = records[i];
        uint32_t r1 = records[i + THR];
        atomicAdd(&hist[r0 & (BINSZ - 1)], 1u);
        atomicAdd(&hist[r1 & (BINSZ - 1)], 1u);
    }
    if (i < shi) atomicAdd(&hist[records[i] & (BINSZ - 1)], 1u);
    __syncthreads();
    histP[(size_t)blockIdx.x * BINSZ + t] = hist[t];
}

__global__ void mergeDinvY(const uint32_t* __restrict__ histP,
                           const float4* __restrict__ x4,
                           float* __restrict__ dinv, uint32_t* __restrict__ deg,
                           ulonglong2* __restrict__ y4q, int split, int n) {
    int t = threadIdx.x, bin = blockIdx.x;
    int node = (bin << BINBITS) + t;
    if (node >= n) return;
    uint32_t c = 0;
    for (int s = 0; s < split; ++s)
        c += histP[(size_t)(bin * split + s) * BINSZ + t];
    float dd = rsqrtf(1.0f + (float)c);
    dinv[node] = dd;
    deg[node] = c;
    float4 xv = x4[node];
    uint32_t q0 = packq(dd * xv.x), q1 = packq(dd * xv.y);
    uint32_t q2 = packq(dd * xv.z), q3 = packq(dd * xv.w);
    ulonglong2 p;
    p.x = ((unsigned long long)q1 << 32) | q0;
    p.y = ((unsigned long long)q3 << 32) | q2;
    y4q[node] = p;
}

// ---------------- layer-1 aggregation (packed u64 atomics) ----------------

__global__ void agg_part(const uint32_t* __restrict__ records,
                         const uint32_t* __restrict__ binStart,
                         const ulonglong2* __restrict__ y4q,
                         unsigned long long* __restrict__ aggP, int split) {
    __shared__ unsigned long long acc[2 * BINSZ];
    int t = threadIdx.x;
    int bin = blockIdx.x / split, sub = blockIdx.x % split;
    acc[t] = 0ull;
    acc[BINSZ + t] = 0ull;
    __syncthreads();
    uint32_t lo = binStart[bin], hi = binStart[bin + 1];
    uint32_t chunk = (hi - lo + split - 1) / split;
    uint32_t slo = lo + sub * chunk;
    uint32_t shi = min(hi, slo + chunk);
    uint32_t i = slo + t;
    for (; i + THR < shi; i += 2 * THR) {          // unroll-2 for ILP
        uint32_t r0 = records[i];
        uint32_t r1 = records[i + THR];
        ulonglong2 y0 = y4q[r0 >> BINBITS];
        ulonglong2 y1 = y4q[r1 >> BINBITS];
        unsigned d0 = r0 & (BINSZ - 1), d1 = r1 & (BINSZ - 1);
        atomicAdd(&acc[d0], y0.x);
        atomicAdd(&acc[BINSZ + d0], y0.y);
        atomicAdd(&acc[d1], y1.x);
        atomicAdd(&acc[BINSZ + d1], y1.y);
    }
    if (i < shi) {
        uint32_t r0 = records[i];
        ulonglong2 y0 = y4q[r0 >> BINBITS];
        unsigned d0 = r0 & (BINSZ - 1);
        atomicAdd(&acc[d0], y0.x);
        atomicAdd(&acc[BINSZ + d0], y0.y);
    }
    __syncthreads();
    unsigned long long* p = aggP + (size_t)blockIdx.x * (2 * BINSZ);
    p[t] = acc[t];
    p[BINSZ + t] = acc[BINSZ + t];
}

__global__ void mergeAggT(const unsigned long long* __restrict__ aggP,
                          const float* __restrict__ dinv, const uint32_t* __restrict__ deg,
                          const float4* __restrict__ x4,
                          const float* __restrict__ W1, const float* __restrict__ b1,
                          const float* __restrict__ W2,
                          float* __restrict__ g, int split, int n) {
    __shared__ float sW1[128], sb1[32], sW2[32];
    int t = threadIdx.x, bin = blockIdx.x;
    if (t < 128) sW1[t] = W1[t];
    else if (t < 160) sb1[t - 128] = b1[t - 128];
    else if (t < 192) sW2[t - 160] = W2[t - 160];
    __syncthreads();
    int node = (bin << BINBITS) + t;
    if (node >= n) return;
    unsigned long long s0lo = 0, s0hi = 0, s1lo = 0, s1hi = 0;
    for (int s = 0; s < split; ++s) {
        const unsigned long long* p = aggP + (size_t)(bin * split + s) * (2 * BINSZ);
        unsigned long long P0 = p[t], P1 = p[BINSZ + t];
        s0lo += (uint32_t)P0; s0hi += (uint32_t)(P0 >> 32);
        s1lo += (uint32_t)P1; s1hi += (uint32_t)(P1 >> 32);
    }
    // exact de-bias + conversion: v in 2^-21 units; split at 2^21 so both
    // halves convert to float exactly (sum magnitude ~4e9 > 2^24).
    long long bias = (long long)deg[node] << 25;   // deg * 16 * 2^21
    const float inv = 1.0f / QS;
    long long v0 = (long long)s0lo - bias, v1 = (long long)s0hi - bias;
    long long v2 = (long long)s1lo - bias, v3 = (long long)s1hi - bias;
    float T0 = (float)(v0 >> 21) + (float)(v0 & 0x1FFFFF) * inv;
    float T1 = (float)(v1 >> 21) + (float)(v1 & 0x1FFFFF) * inv;
    float T2 = (float)(v2 >> 21) + (float)(v2 & 0x1FFFFF) * inv;
    float T3 = (float)(v3 >> 21) + (float)(v3 & 0x1FFFFF) * inv;
    float dd = dinv[node];
    float4 xv = x4[node];
    float a0 = dd * (T0 + dd * xv.x), a1 = dd * (T1 + dd * xv.y);
    float a2 = dd * (T2 + dd * xv.z), a3 = dd * (T3 + dd * xv.w);
    float hv = 0.f;
#pragma unroll
    for (int j = 0; j < 32; ++j) {
        float o = fmaf(a0, sW1[j], fmaf(a1, sW1[32 + j],
                  fmaf(a2, sW1[64 + j], fmaf(a3, sW1[96 + j], sb1[j]))));
        hv += fmaxf(o, 0.f) * sW2[j];
    }
    g[node] = dd * hv;
}

// ---------------- layer-2 ----------------

__global__ void out_part(const uint32_t* __restrict__ records,
                         const uint32_t* __restrict__ binStart,
                         const float* __restrict__ g,
                         float* __restrict__ outP, int split) {
    __shared__ float accg[BINSZ];
    int t = threadIdx.x;
    int bin = blockIdx.x / split, sub = blockIdx.x % split;
    accg[t] = 0.f;
    __syncthreads();
    uint32_t lo = binStart[bin], hi = binStart[bin + 1];
    uint32_t chunk = (hi - lo + split - 1) / split;
    uint32_t slo = lo + sub * chunk;
    uint32_t shi = min(hi, slo + chunk);
    uint32_t i = slo + t;
    for (; i + THR < shi; i += 2 * THR) {
        uint32_t r0 = records[i];
        uint32_t r1 = records[i + THR];
        float g0 = g[r0 >> BINBITS];
        float g1 = g[r1 >> BINBITS];
        atomicAdd(&accg[r0 & (BINSZ - 1)], g0);
        atomicAdd(&accg[r1 & (BINSZ - 1)], g1);
    }
    if (i < shi) {
        uint32_t r0 = records[i];
        atomicAdd(&accg[r0 & (BINSZ - 1)], g[r0 >> BINBITS]);
    }
    __syncthreads();
    outP[(size_t)blockIdx.x * BINSZ + t] = accg[t];
}

__global__ void mergeOutK(const float* __restrict__ outP, const float* __restrict__ g,
                          const float* __restrict__ dinv, const float* __restrict__ b2,
                          float* __restrict__ out, int split, int n) {
    int t = threadIdx.x, bin = blockIdx.x;
    int node = (bin << BINBITS) + t;
    if (node >= n) return;
    float s = 0.f;
    for (int k = 0; k < split; ++k)
        s += outP[(size_t)(bin * split + k) * BINSZ + t];
    float v = dinv[node] * (s + g[node]) + b2[0];
    out[node] = 1.0f / (1.0f + expf(-v));
}

// ---------------- launcher ----------------

extern "C" void kernel_launch(void* const* d_in, const int* in_sizes, int n_in,
                              void* d_out, int out_size, void* d_ws, size_t ws_size,
                              hipStream_t stream) {
    const float* x  = (const float*)d_in[0];
    const int*   ei = (const int*)d_in[1];
    const float* W1 = (const float*)d_in[2];
    const float* b1 = (const float*)d_in[3];
    const float* W2 = (const float*)d_in[4];
    const float* b2 = (const float*)d_in[5];
    float* out = (float*)d_out;

    const int n = in_sizes[0] / 4;            // 100000
    const int e = in_sizes[1] / 2;            // 3200000
    const int* src = ei;
    const int* dst = ei + e;

    const int nb = (n + BINSZ - 1) >> BINBITS;   // 391

    size_t recB  = ((size_t)e * 4 + 15) & ~(size_t)15;
    size_t bcB   = ((size_t)nb * EBC * 4 + 15) & ~(size_t)15;
    size_t bsB   = ((size_t)(2 * nb + 2) * 4 + 15) & ~(size_t)15;
    size_t dinvB = ((size_t)n * 4 + 15) & ~(size_t)15;
    size_t degB  = ((size_t)n * 4 + 15) & ~(size_t)15;
    size_t gB    = ((size_t)n * 4 + 15) & ~(size_t)15;
    size_t y4qB  = ((size_t)n * 16 + 15) & ~(size_t)15;
    size_t fixed = recB + bcB + bsB + dinvB + degB + gB + y4qB;

    auto arena_sz = [&](int s) { return (size_t)nb * s * (2 * BINSZ) * 8; };

    int split;
    if      (ws_size >= fixed + arena_sz(8)) split = 8;
    else if (ws_size >= fixed + arena_sz(4)) split = 4;
    else if (ws_size >= fixed + arena_sz(2)) split = 2;
    else                                     split = 1;

    char* p = (char*)d_ws;
    uint32_t*   records  = (uint32_t*)p;      p += recB;
    uint32_t*   bc       = (uint32_t*)p;      p += bcB;
    uint32_t*   binStart = (uint32_t*)p;      p += bsB;
    uint32_t*   binSum   = binStart + nb + 1;
    float*      dinv     = (float*)p;         p += dinvB;
    uint32_t*   deg      = (uint32_t*)p;      p += degB;
    float*      gbuf     = (float*)p;         p += gB;
    ulonglong2* y4q      = (ulonglong2*)p;    p += y4qB;
    void*       arena    = (void*)p;          // partials (deg/agg/out reuse sequentially)

    const float4* x4 = (const float4*)x;

    countK<<<EBC, THR, 0, stream>>>(dst, bc, e, nb);
    scan1K<<<nb, EBC, 0, stream>>>(bc, binSum);
    scan2K<<<1, 512, 0, stream>>>(binSum, binStart, nb, e);
    fillK <<<EBC, THR, 0, stream>>>(src, dst, bc, binStart, records, e, nb);

    deg_part<<<nb * split, THR, 0, stream>>>(records, binStart, (uint32_t*)arena, split);
    mergeDinvY<<<nb, THR, 0, stream>>>((const uint32_t*)arena, x4, dinv, deg, y4q, split, n);
    agg_part<<<nb * split, THR, 0, stream>>>(records, binStart, y4q,
                                             (unsigned long long*)arena, split);
    mergeAggT<<<nb, THR, 0, stream>>>((const unsigned long long*)arena, dinv, deg, x4,
                                      W1, b1, W2, gbuf, split, n);
    out_part<<<nb * split, THR, 0, stream>>>(records, binStart, gbuf, (float*)arena, split);
    mergeOutK<<<nb, THR, 0, stream>>>((const float*)arena, gbuf, dinv, b2, out, split, n);
}

// Round 10
// 97.134 us; speedup vs baseline: 10.1344x; 1.0817x over previous
//
#include <hip/hip_runtime.h>
#include <math.h>
#include <stdint.h>

// 2-layer GCN anomaly scorer — binned counting-sort + LDS accumulation.
// R4: device atomics write through HBM -> 984us. R5: binned LDS 358us.
// R6: split4 -> 315us. R7: 2-level scan -> 160us. R8: split8 + u64 packed
// LDS atomics -> 115us (fillK write-amplified at EBC=1024). R9: EBC=256 +
// XCD swizzle + exact i64 conversion -> 105us. R10: vectorize ALL sweeps
// (int4/uint4, 4 edges/records per thread-iter) with 4-padded bin regions
// (sentinel 0xFFFFFFFF) for alignment.
//
// Math: agg[d] = dinv[d]*(sum_{s->d} y[s] + y[d]),  y = dinv.*x
//       g      = dinv .* (relu(agg@W1+b1)@W2)
//       out[d] = sigmoid(dinv[d]*(sum_{s->d} g[s] + g[d]) + b2)
// Fixed-point: q(v) = rn((v+16)*2^21); fields (f0,f1),(f2,f3) in two u64s.

#define BINBITS 8
#define BINSZ   256
#define NBMAX   512
#define EBC     256      // edge-chunk blocks for count/fill
#define THR     256
#define QS      2097152.0f   // 2^21
#define SENT    0xFFFFFFFFu

__device__ __forceinline__ uint32_t packq(float v) {
    return __float2uint_rn(fmaf(v, QS, 16.0f * QS));
}

// ---------------- sort phase ----------------

__global__ void countK(const int* __restrict__ dst, uint32_t* __restrict__ bc,
                       int e, int nb) {
    __shared__ uint32_t cnt[NBMAX];
    int t = threadIdx.x, b = blockIdx.x;
    for (int i = t; i < nb; i += THR) cnt[i] = 0;
    __syncthreads();
    int epb = (e + EBC - 1) / EBC;
    int lo = b * epb, hi = min(e, lo + epb);
    if (((lo | hi) & 3) == 0 && (((uintptr_t)dst & 15) == 0)) {
        const int4* dst4 = (const int4*)dst;
        for (int i = lo / 4 + t; i < hi / 4; i += THR) {
            int4 v = dst4[i];
            atomicAdd(&cnt[((unsigned)v.x) >> BINBITS], 1u);
            atomicAdd(&cnt[((unsigned)v.y) >> BINBITS], 1u);
            atomicAdd(&cnt[((unsigned)v.z) >> BINBITS], 1u);
            atomicAdd(&cnt[((unsigned)v.w) >> BINBITS], 1u);
        }
    } else {
        for (int i = lo + t; i < hi; i += THR)
            atomicAdd(&cnt[((unsigned)dst[i]) >> BINBITS], 1u);
    }
    __syncthreads();
    for (int i = t; i < nb; i += THR) bc[(size_t)i * EBC + b] = cnt[i];
}

// per-bin exclusive scan of the EBC per-block counts (block == EBC threads)
__global__ void scan1K(uint32_t* __restrict__ bc, uint32_t* __restrict__ binSum) {
    __shared__ uint32_t s[EBC];
    int t = threadIdx.x, bin = blockIdx.x;
    uint32_t v = bc[(size_t)bin * EBC + t];
    s[t] = v;
    __syncthreads();
    for (int off = 1; off < EBC; off <<= 1) {
        uint32_t u = (t >= off) ? s[t - off] : 0u;
        __syncthreads();
        s[t] += u;
        __syncthreads();
    }
    bc[(size_t)bin * EBC + t] = s[t] - v;           // exclusive
    if (t == EBC - 1) binSum[bin] = s[t];
}

// padded (multiple-of-4) exclusive scan of bin sums -> binStart
__global__ void scan2K(const uint32_t* __restrict__ binSum,
                       uint32_t* __restrict__ binStart, int nb) {
    __shared__ uint32_t s[512];
    int t = threadIdx.x;
    uint32_t v = (t < nb) ? ((binSum[t] + 3u) & ~3u) : 0u;
    s[t] = v;
    __syncthreads();
    for (int off = 1; off < 512; off <<= 1) {
        uint32_t u = (t >= off) ? s[t - off] : 0u;
        __syncthreads();
        s[t] += u;
        __syncthreads();
    }
    if (t < nb) binStart[t] = s[t] - v;
    if (t == nb - 1) binStart[nb] = s[t];           // padded total
}

// fill pad slots (between real count and padded bin end) with sentinels
__global__ void gapK(const uint32_t* __restrict__ binStart,
                     const uint32_t* __restrict__ binSum,
                     uint32_t* __restrict__ records, int nb) {
    int i = blockIdx.x * blockDim.x + threadIdx.x;
    int bin = i >> 2, j = i & 3;
    if (bin >= nb) return;
    uint32_t s = binStart[bin] + binSum[bin] + j;
    if (s < binStart[bin + 1]) records[s] = SENT;
}

__global__ void fillK(const int* __restrict__ src, const int* __restrict__ dst,
                      const uint32_t* __restrict__ bc,
                      const uint32_t* __restrict__ binStart,
                      uint32_t* __restrict__ records, int e, int nb) {
    __shared__ uint32_t cur[NBMAX];
    int t = threadIdx.x;
    // XCD-contiguous chunk swizzle (R9): same-XCD blocks take contiguous
    // edge chunks so shared record lines stay in one XCD's L2.
    int b = (blockIdx.x & 7) * (EBC / 8) + (blockIdx.x >> 3);
    for (int i = t; i < nb; i += THR)
        cur[i] = bc[(size_t)i * EBC + b] + binStart[i];
    __syncthreads();
    int epb = (e + EBC - 1) / EBC;
    int lo = b * epb, hi = min(e, lo + epb);
    if (((lo | hi) & 3) == 0 && (((uintptr_t)src & 15) == 0) && (((uintptr_t)dst & 15) == 0)) {
        const int4* src4 = (const int4*)src;
        const int4* dst4 = (const int4*)dst;
        for (int i = lo / 4 + t; i < hi / 4; i += THR) {
            int4 dv = dst4[i];
            int4 sv = src4[i];
            unsigned d0 = (unsigned)dv.x, d1 = (unsigned)dv.y;
            unsigned d2 = (unsigned)dv.z, d3 = (unsigned)dv.w;
            uint32_t p0 = atomicAdd(&cur[d0 >> BINBITS], 1u);
            records[p0] = (((unsigned)sv.x) << BINBITS) | (d0 & (BINSZ - 1));
            uint32_t p1 = atomicAdd(&cur[d1 >> BINBITS], 1u);
            records[p1] = (((unsigned)sv.y) << BINBITS) | (d1 & (BINSZ - 1));
            uint32_t p2 = atomicAdd(&cur[d2 >> BINBITS], 1u);
            records[p2] = (((unsigned)sv.z) << BINBITS) | (d2 & (BINSZ - 1));
            uint32_t p3 = atomicAdd(&cur[d3 >> BINBITS], 1u);
            records[p3] = (((unsigned)sv.w) << BINBITS) | (d3 & (BINSZ - 1));
        }
    } else {
        for (int i = lo + t; i < hi; i += THR) {
            unsigned d = (unsigned)dst[i];
            unsigned s = (unsigned)src[i];
            uint32_t slot = atomicAdd(&cur[d >> BINBITS], 1u);
            records[slot] = (s << BINBITS) | (d & (BINSZ - 1));
        }
    }
}

// ---------------- degree / dinv / packed y ----------------

__global__ void deg_part(const uint32_t* __restrict__ records,
                         const uint32_t* __restrict__ binStart,
                         uint32_t* __restrict__ histP, int split) {
    __shared__ uint32_t hist[BINSZ];
    int t = threadIdx.x;
    int bin = blockIdx.x / split, sub = blockIdx.x % split;
    hist[t] = 0u;
    __syncthreads();
    uint32_t lo = binStart[bin], hi = binStart[bin + 1];
    uint32_t chunk = (((hi - lo + split - 1) / split) + 3u) & ~3u;
    uint32_t slo = lo + sub * chunk;
    uint32_t shi = min(hi, slo + chunk);
    const uint4* rec4 = (const uint4*)records;
    for (uint32_t i = slo / 4 + t; i < shi / 4; i += THR) {
        uint4 r = rec4[i];
        if (r.x != SENT) atomicAdd(&hist[r.x & (BINSZ - 1)], 1u);
        if (r.y != SENT) atomicAdd(&hist[r.y & (BINSZ - 1)], 1u);
        if (r.z != SENT) atomicAdd(&hist[r.z & (BINSZ - 1)], 1u);
        if (r.w != SENT) atomicAdd(&hist[r.w & (BINSZ - 1)], 1u);
    }
    __syncthreads();
    histP[(size_t)blockIdx.x * BINSZ + t] = hist[t];
}

__global__ void mergeDinvY(const uint32_t* __restrict__ histP,
                           const float4* __restrict__ x4,
                           float* __restrict__ dinv, uint32_t* __restrict__ deg,
                           ulonglong2* __restrict__ y4q, int split, int n) {
    int t = threadIdx.x, bin = blockIdx.x;
    int node = (bin << BINBITS) + t;
    if (node >= n) return;
    uint32_t c = 0;
    for (int s = 0; s < split; ++s)
        c += histP[(size_t)(bin * split + s) * BINSZ + t];
    float dd = rsqrtf(1.0f + (float)c);
    dinv[node] = dd;
    deg[node] = c;
    float4 xv = x4[node];
    uint32_t q0 = packq(dd * xv.x), q1 = packq(dd * xv.y);
    uint32_t q2 = packq(dd * xv.z), q3 = packq(dd * xv.w);
    ulonglong2 p;
    p.x = ((unsigned long long)q1 << 32) | q0;
    p.y = ((unsigned long long)q3 << 32) | q2;
    y4q[node] = p;
}

// ---------------- layer-1 aggregation (packed u64 atomics) ----------------

__global__ void agg_part(const uint32_t* __restrict__ records,
                         const uint32_t* __restrict__ binStart,
                         const ulonglong2* __restrict__ y4q,
                         unsigned long long* __restrict__ aggP, int split) {
    __shared__ unsigned long long acc[2 * BINSZ];
    int t = threadIdx.x;
    int bin = blockIdx.x / split, sub = blockIdx.x % split;
    acc[t] = 0ull;
    acc[BINSZ + t] = 0ull;
    __syncthreads();
    uint32_t lo = binStart[bin], hi = binStart[bin + 1];
    uint32_t chunk = (((hi - lo + split - 1) / split) + 3u) & ~3u;
    uint32_t slo = lo + sub * chunk;
    uint32_t shi = min(hi, slo + chunk);
    const uint4* rec4 = (const uint4*)records;
    for (uint32_t i = slo / 4 + t; i < shi / 4; i += THR) {
        uint4 r = rec4[i];
        // issue all 4 gathers before the atomics (sentinel -> safe idx 0)
        unsigned s0 = (r.x == SENT) ? 0u : (r.x >> BINBITS);
        unsigned s1 = (r.y == SENT) ? 0u : (r.y >> BINBITS);
        unsigned s2 = (r.z == SENT) ? 0u : (r.z >> BINBITS);
        unsigned s3 = (r.w == SENT) ? 0u : (r.w >> BINBITS);
        ulonglong2 y0 = y4q[s0];
        ulonglong2 y1 = y4q[s1];
        ulonglong2 y2 = y4q[s2];
        ulonglong2 y3 = y4q[s3];
        if (r.x != SENT) { unsigned d = r.x & (BINSZ - 1); atomicAdd(&acc[d], y0.x); atomicAdd(&acc[BINSZ + d], y0.y); }
        if (r.y != SENT) { unsigned d = r.y & (BINSZ - 1); atomicAdd(&acc[d], y1.x); atomicAdd(&acc[BINSZ + d], y1.y); }
        if (r.z != SENT) { unsigned d = r.z & (BINSZ - 1); atomicAdd(&acc[d], y2.x); atomicAdd(&acc[BINSZ + d], y2.y); }
        if (r.w != SENT) { unsigned d = r.w & (BINSZ - 1); atomicAdd(&acc[d], y3.x); atomicAdd(&acc[BINSZ + d], y3.y); }
    }
    __syncthreads();
    unsigned long long* p = aggP + (size_t)blockIdx.x * (2 * BINSZ);
    p[t] = acc[t];
    p[BINSZ + t] = acc[BINSZ + t];
}

__global__ void mergeAggT(const unsigned long long* __restrict__ aggP,
                          const float* __restrict__ dinv, const uint32_t* __restrict__ deg,
                          const float4* __restrict__ x4,
                          const float* __restrict__ W1, const float* __restrict__ b1,
                          const float* __restrict__ W2,
                          float* __restrict__ g, int split, int n) {
    __shared__ float sW1[128], sb1[32], sW2[32];
    int t = threadIdx.x, bin = blockIdx.x;
    if (t < 128) sW1[t] = W1[t];
    else if (t < 160) sb1[t - 128] = b1[t - 128];
    else if (t < 192) sW2[t - 160] = W2[t - 160];
    __syncthreads();
    int node = (bin << BINBITS) + t;
    if (node >= n) return;
    unsigned long long s0lo = 0, s0hi = 0, s1lo = 0, s1hi = 0;
    for (int s = 0; s < split; ++s) {
        const unsigned long long* p = aggP + (size_t)(bin * split + s) * (2 * BINSZ);
        unsigned long long P0 = p[t], P1 = p[BINSZ + t];
        s0lo += (uint32_t)P0; s0hi += (uint32_t)(P0 >> 32);
        s1lo += (uint32_t)P1; s1hi += (uint32_t)(P1 >> 32);
    }
    // exact de-bias + conversion (R9): split at 2^21 so both halves are exact.
    long long bias = (long long)deg[node] << 25;   // deg * 16 * 2^21
    const float inv = 1.0f / QS;
    long long v0 = (long long)s0lo - bias, v1 = (long long)s0hi - bias;
    long long v2 = (long long)s1lo - bias, v3 = (long long)s1hi - bias;
    float T0 = (float)(v0 >> 21) + (float)(v0 & 0x1FFFFF) * inv;
    float T1 = (float)(v1 >> 21) + (float)(v1 & 0x1FFFFF) * inv;
    float T2 = (float)(v2 >> 21) + (float)(v2 & 0x1FFFFF) * inv;
    float T3 = (float)(v3 >> 21) + (float)(v3 & 0x1FFFFF) * inv;
    float dd = dinv[node];
    float4 xv = x4[node];
    float a0 = dd * (T0 + dd * xv.x), a1 = dd * (T1 + dd * xv.y);
    float a2 = dd * (T2 + dd * xv.z), a3 = dd * (T3 + dd * xv.w);
    float hv = 0.f;
#pragma unroll
    for (int j = 0; j < 32; ++j) {
        float o = fmaf(a0, sW1[j], fmaf(a1, sW1[32 + j],
                  fmaf(a2, sW1[64 + j], fmaf(a3, sW1[96 + j], sb1[j]))));
        hv += fmaxf(o, 0.f) * sW2[j];
    }
    g[node] = dd * hv;
}

// ---------------- layer-2 ----------------

__global__ void out_part(const uint32_t* __restrict__ records,
                         const uint32_t* __restrict__ binStart,
                         const float* __restrict__ g,
                         float* __restrict__ outP, int split) {
    __shared__ float accg[BINSZ];
    int t = threadIdx.x;
    int bin = blockIdx.x / split, sub = blockIdx.x % split;
    accg[t] = 0.f;
    __syncthreads();
    uint32_t lo = binStart[bin], hi = binStart[bin + 1];
    uint32_t chunk = (((hi - lo + split - 1) / split) + 3u) & ~3u;
    uint32_t slo = lo + sub * chunk;
    uint32_t shi = min(hi, slo + chunk);
    const uint4* rec4 = (const uint4*)records;
    for (uint32_t i = slo / 4 + t; i < shi / 4; i += THR) {
        uint4 r = rec4[i];
        unsigned s0 = (r.x == SENT) ? 0u : (r.x >> BINBITS);
        unsigned s1 = (r.y == SENT) ? 0u : (r.y >> BINBITS);
        unsigned s2 = (r.z == SENT) ? 0u : (r.z >> BINBITS);
        unsigned s3 = (r.w == SENT) ? 0u : (r.w >> BINBITS);
        float g0 = g[s0], g1 = g[s1], g2 = g[s2], g3 = g[s3];
        if (r.x != SENT) atomicAdd(&accg[r.x & (BINSZ - 1)], g0);
        if (r.y != SENT) atomicAdd(&accg[r.y & (BINSZ - 1)], g1);
        if (r.z != SENT) atomicAdd(&accg[r.z & (BINSZ - 1)], g2);
        if (r.w != SENT) atomicAdd(&accg[r.w & (BINSZ - 1)], g3);
    }
    __syncthreads();
    outP[(size_t)blockIdx.x * BINSZ + t] = accg[t];
}

__global__ void mergeOutK(const float* __restrict__ outP, const float* __restrict__ g,
                          const float* __restrict__ dinv, const float* __restrict__ b2,
                          float* __restrict__ out, int split, int n) {
    int t = threadIdx.x, bin = blockIdx.x;
    int node = (bin << BINBITS) + t;
    if (node >= n) return;
    float s = 0.f;
    for (int k = 0; k < split; ++k)
        s += outP[(size_t)(bin * split + k) * BINSZ + t];
    float v = dinv[node] * (s + g[node]) + b2[0];
    out[node] = 1.0f / (1.0f + expf(-v));
}

// ---------------- launcher ----------------

extern "C" void kernel_launch(void* const* d_in, const int* in_sizes, int n_in,
                              void* d_out, int out_size, void* d_ws, size_t ws_size,
                              hipStream_t stream) {
    const float* x  = (const float*)d_in[0];
    const int*   ei = (const int*)d_in[1];
    const float* W1 = (const float*)d_in[2];
    const float* b1 = (const float*)d_in[3];
    const float* W2 = (const float*)d_in[4];
    const float* b2 = (const float*)d_in[5];
    float* out = (float*)d_out;

    const int n = in_sizes[0] / 4;            // 100000
    const int e = in_sizes[1] / 2;            // 3200000
    const int* src = ei;
    const int* dst = ei + e;

    const int nb = (n + BINSZ - 1) >> BINBITS;   // 391

    size_t recB  = (((size_t)e + 4 * (size_t)nb) * 4 + 15) & ~(size_t)15;  // padded bins
    size_t bcB   = ((size_t)nb * EBC * 4 + 15) & ~(size_t)15;
    size_t bsB   = ((size_t)(2 * nb + 2) * 4 + 15) & ~(size_t)15;
    size_t dinvB = ((size_t)n * 4 + 15) & ~(size_t)15;
    size_t degB  = ((size_t)n * 4 + 15) & ~(size_t)15;
    size_t gB    = ((size_t)n * 4 + 15) & ~(size_t)15;
    size_t y4qB  = ((size_t)n * 16 + 15) & ~(size_t)15;
    size_t fixed = recB + bcB + bsB + dinvB + degB + gB + y4qB;

    auto arena_sz = [&](int s) { return (size_t)nb * s * (2 * BINSZ) * 8; };

    int split;
    if      (ws_size >= fixed + arena_sz(8)) split = 8;
    else if (ws_size >= fixed + arena_sz(4)) split = 4;
    else if (ws_size >= fixed + arena_sz(2)) split = 2;
    else                                     split = 1;

    char* p = (char*)d_ws;
    uint32_t*   records  = (uint32_t*)p;      p += recB;
    uint32_t*   bc       = (uint32_t*)p;      p += bcB;
    uint32_t*   binStart = (uint32_t*)p;      p += bsB;
    uint32_t*   binSum   = binStart + nb + 1;
    float*      dinv     = (float*)p;         p += dinvB;
    uint32_t*   deg      = (uint32_t*)p;      p += degB;
    float*      gbuf     = (float*)p;         p += gB;
    ulonglong2* y4q      = (ulonglong2*)p;    p += y4qB;
    void*       arena    = (void*)p;          // partials (deg/agg/out reuse sequentially)

    const float4* x4 = (const float4*)x;

    countK<<<EBC, THR, 0, stream>>>(dst, bc, e, nb);
    scan1K<<<nb, EBC, 0, stream>>>(bc, binSum);
    scan2K<<<1, 512, 0, stream>>>(binSum, binStart, nb);
    gapK  <<<(nb * 4 + THR - 1) / THR, THR, 0, stream>>>(binStart, binSum, records, nb);
    fillK <<<EBC, THR, 0, stream>>>(src, dst, bc, binStart, records, e, nb);

    deg_part<<<nb * split, THR, 0, stream>>>(records, binStart, (uint32_t*)arena, split);
    mergeDinvY<<<nb, THR, 0, stream>>>((const uint32_t*)arena, x4, dinv, deg, y4q, split, n);
    agg_part<<<nb * split, THR, 0, stream>>>(records, binStart, y4q,
                                             (unsigned long long*)arena, split);
    mergeAggT<<<nb, THR, 0, stream>>>((const unsigned long long*)arena, dinv, deg, x4,
                                      W1, b1, W2, gbuf, split, n);
    out_part<<<nb * split, THR, 0, stream>>>(records, binStart, gbuf, (float*)arena, split);
    mergeOutK<<<nb, THR, 0, stream>>>((const float*)arena, gbuf, dinv, b2, out, split, n);
}